// Round 34
// baseline (541.088 us; speedup 1.0000x reference)
//
#include <hip/hip_runtime.h>

#define NN 20000
#define NE 320000
#define CDIM 16
#define MID 32
#define EPSF 1e-8f

#define SCHED_FENCE() __builtin_amdgcn_sched_barrier(0)

// ---- workspace word (4B) offsets ----
#define OFF_DEGI   848         // 20000 int
#define ZERO_WORDS 20848
#define OFF_ROWPTR 20848       // 20001 int
#define OFF_CURSOR 40864       // 20000 int (dead after k_scatter; CC2 reuses it)
#define OFF_CC2    40864       // 192 f (fin2 output, new path)
#define OFF_EORDER 60864       // 320000 int
#define OFF_SRCS   380864      // 320000 int  (src in sorted order)
#define OFF_WSRT   700864      // 320000 f    (w in sorted order)
#define OFF_FW1A   1020864     // 192
#define OFF_FW1B   1021056     // 192
#define OFF_FC1    1021248     // 192
#define OFF_BN2A   1021440     // 192
#define OFF_FC2    1021632     // 192
#define OFF_FW2T   1021824     // 6144
#define OFF_ECS    1027968     // 1280000 (float4, SORTED order)
#define OFF_H0N    2307968     // 320000
#define OFF_H1N    2627968     // 960000
#define OFF_MSGA0  3587968     // 5120000
#define OFF_MSGA1  8707968     // 15360000 (GROUP-MAJOR: 4 planes of NE*12)
#define OFF_MSGB   24067968    // 2560000 (8 f/edge, padded)
#define OFF_PRE    26627968    // 6 planes of NE*32 f (pre-activations, NEW path)
#define WS_WORDS_NEEDED 88067968ULL   // OFF_PRE + 6*NE*32

#define Y0C   0.28209479177387814f
#define Y1C   0.4886025119029199f
#define Y2C1  1.0925484305920792f
#define Y2C2  0.31539156525252005f
#define Y2C3  0.5462742152960396f
#define S2C   0.7071067811865476f
#define S6C   0.4082482904638631f
#define K0C   0.16286750396763996f

__device__ __forceinline__ void atomAddD(double* p, double v) {
  unsafeAtomicAdd(p, v);
}

// Single-edge MLP, LDS weights, float4 (ds_read_b128) reads. (old path)
__device__ __forceinline__ void mlpH_lds(
    const float* __restrict__ a1, const float* __restrict__ b1v,
    const float* __restrict__ c1, const float* __restrict__ c2,
    const float* __restrict__ W2T, float we, float r, float* H) {
  float h[MID];
#pragma unroll
  for (int j4 = 0; j4 < 8; ++j4) {
    float4 av = ((const float4*)a1)[j4];
    float4 bv = ((const float4*)b1v)[j4];
    float4 cv = ((const float4*)c1)[j4];
    h[4 * j4 + 0] = fmaxf(fmaf(we, av.x, fmaf(r, bv.x, cv.x)), 0.0f);
    h[4 * j4 + 1] = fmaxf(fmaf(we, av.y, fmaf(r, bv.y, cv.y)), 0.0f);
    h[4 * j4 + 2] = fmaxf(fmaf(we, av.z, fmaf(r, bv.z, cv.z)), 0.0f);
    h[4 * j4 + 3] = fmaxf(fmaf(we, av.w, fmaf(r, bv.w, cv.w)), 0.0f);
  }
  SCHED_FENCE();
#pragma unroll
  for (int jg = 0; jg < 8; ++jg) {
#pragma unroll
    for (int jq = 0; jq < 4; ++jq) {
      const int j = jg * 4 + jq;
      float acc = c2[j];
      const float4* wp = (const float4*)(W2T + j * MID);
#pragma unroll
      for (int i4 = 0; i4 < 8; ++i4) {
        float4 wv = wp[i4];
        acc = fmaf(h[4 * i4 + 0], wv.x, acc);
        acc = fmaf(h[4 * i4 + 1], wv.y, acc);
        acc = fmaf(h[4 * i4 + 2], wv.z, acc);
        acc = fmaf(h[4 * i4 + 3], wv.w, acc);
      }
      H[j] = fmaxf(acc, 0.0f);
    }
    SCHED_FENCE();
  }
}

// Two-edge MLP, LDS weights, float4 reads — old-path passB.
__device__ __forceinline__ void mlpH2_lds(
    const float* __restrict__ a1, const float* __restrict__ b1v,
    const float* __restrict__ c1, const float* __restrict__ c2,
    const float* __restrict__ W2T,
    float weA, float rA, float weB, float rB,
    float* HA, float* HB) {
  float hA[MID], hB[MID];
#pragma unroll
  for (int j4 = 0; j4 < 8; ++j4) {
    float4 av = ((const float4*)a1)[j4];
    float4 bv = ((const float4*)b1v)[j4];
    float4 cv = ((const float4*)c1)[j4];
    hA[4 * j4 + 0] = fmaxf(fmaf(weA, av.x, fmaf(rA, bv.x, cv.x)), 0.0f);
    hB[4 * j4 + 0] = fmaxf(fmaf(weB, av.x, fmaf(rB, bv.x, cv.x)), 0.0f);
    hA[4 * j4 + 1] = fmaxf(fmaf(weA, av.y, fmaf(rA, bv.y, cv.y)), 0.0f);
    hB[4 * j4 + 1] = fmaxf(fmaf(weB, av.y, fmaf(rB, bv.y, cv.y)), 0.0f);
    hA[4 * j4 + 2] = fmaxf(fmaf(weA, av.z, fmaf(rA, bv.z, cv.z)), 0.0f);
    hB[4 * j4 + 2] = fmaxf(fmaf(weB, av.z, fmaf(rB, bv.z, cv.z)), 0.0f);
    hA[4 * j4 + 3] = fmaxf(fmaf(weA, av.w, fmaf(rA, bv.w, cv.w)), 0.0f);
    hB[4 * j4 + 3] = fmaxf(fmaf(weB, av.w, fmaf(rB, bv.w, cv.w)), 0.0f);
  }
  SCHED_FENCE();
#pragma unroll
  for (int jg = 0; jg < 8; ++jg) {
#pragma unroll
    for (int jq = 0; jq < 4; ++jq) {
      const int j = jg * 4 + jq;
      float c2v = c2[j];
      float accA = c2v, accB = c2v;
      const float4* wp = (const float4*)(W2T + j * MID);
#pragma unroll
      for (int i4 = 0; i4 < 8; ++i4) {
        float4 wv = wp[i4];
        accA = fmaf(hA[4 * i4 + 0], wv.x, accA);
        accB = fmaf(hB[4 * i4 + 0], wv.x, accB);
        accA = fmaf(hA[4 * i4 + 1], wv.y, accA);
        accB = fmaf(hB[4 * i4 + 1], wv.y, accB);
        accA = fmaf(hA[4 * i4 + 2], wv.z, accA);
        accB = fmaf(hB[4 * i4 + 2], wv.z, accB);
        accA = fmaf(hA[4 * i4 + 3], wv.w, accA);
        accB = fmaf(hB[4 * i4 + 3], wv.w, accB);
      }
      HA[j] = fmaxf(accA, 0.0f);
      HB[j] = fmaxf(accB, 0.0f);
    }
    SCHED_FENCE();
  }
}

// NEW path: H[32] = relu(a2*P + cc) from a stored pre-activation row.
__device__ __forceinline__ void loadH_P(
    const float4* __restrict__ pp, const float* __restrict__ a2,
    const float* __restrict__ cc, float* H) {
#pragma unroll
  for (int j4 = 0; j4 < 8; ++j4) {
    float4 v = pp[j4];
    float4 av = ((const float4*)a2)[j4];
    float4 cv = ((const float4*)cc)[j4];
    H[4 * j4 + 0] = fmaxf(fmaf(av.x, v.x, cv.x), 0.0f);
    H[4 * j4 + 1] = fmaxf(fmaf(av.y, v.y, cv.y), 0.0f);
    H[4 * j4 + 2] = fmaxf(fmaf(av.z, v.z, cv.z), 0.0f);
    H[4 * j4 + 3] = fmaxf(fmaf(av.w, v.w, cv.w), 0.0f);
  }
  SCHED_FENCE();
}

// ---- degree histogram ----
__global__ __launch_bounds__(256) void k_hist(
    const int* __restrict__ dst, float* __restrict__ ws) {
  int e = blockIdx.x * blockDim.x + threadIdx.x;
  if (e >= NE) return;
  atomicAdd((int*)ws + OFF_DEGI + dst[e], 1);
}

// ---- scan ----
__global__ void k_scan(float* __restrict__ ws) {
  __shared__ int buf[256];
  __shared__ int carry;
  const int* degi = (const int*)ws + OFF_DEGI;
  int* rowptr = (int*)ws + OFF_ROWPTR;
  int* cursor = (int*)ws + OFF_CURSOR;
  int tid = threadIdx.x;
  if (tid == 0) carry = 0;
  __syncthreads();
  for (int base = 0; base < NN; base += 256) {
    int v = (base + tid < NN) ? degi[base + tid] : 0;
    buf[tid] = v;
    __syncthreads();
    for (int off = 1; off < 256; off <<= 1) {
      int t = buf[tid];
      int add = (tid >= off) ? buf[tid - off] : 0;
      __syncthreads();
      buf[tid] = t + add;
      __syncthreads();
    }
    int excl = buf[tid] - v;
    if (base + tid < NN) {
      rowptr[base + tid] = carry + excl;
      cursor[base + tid] = carry + excl;
    }
    __syncthreads();
    if (tid == 255) carry += buf[255];
    __syncthreads();
  }
  if (tid == 0) rowptr[NN] = carry;
}

__global__ __launch_bounds__(256) void k_scatter(
    const int* __restrict__ dst, float* __restrict__ ws) {
  int e = blockIdx.x * blockDim.x + threadIdx.x;
  if (e >= NE) return;
  int* cursor = (int*)ws + OFF_CURSOR;
  int* eorder = (int*)ws + OFF_EORDER;
  int d = dst[e];
  int p = atomicAdd(cursor + d, 1);
  eorder[p] = e;
}

// ---- geo: gather edge data into SORTED order + f64 stats1 ----
__global__ __launch_bounds__(256) void k_geo(
    const int* __restrict__ src, const int* __restrict__ dst,
    const float* __restrict__ pos, const float* __restrict__ w,
    float* __restrict__ ws) {
  __shared__ double sred[20];
  double lw = 0, lr = 0, lww = 0, lrr = 0, lwr = 0;
  const int* eorder = (const int*)ws + OFF_EORDER;
  int* srcs = (int*)ws + OFF_SRCS;
  float* wsrt = ws + OFF_WSRT;
  float4* ecs = (float4*)(ws + OFF_ECS);
  for (int t = blockIdx.x * blockDim.x + threadIdx.x; t < NE;
       t += gridDim.x * blockDim.x) {
    int e = eorder[t];
    int s = src[e], d = dst[e];
    float dx = pos[3 * d + 0] - pos[3 * s + 0];
    float dy = pos[3 * d + 1] - pos[3 * s + 1];
    float dz = pos[3 * d + 2] - pos[3 * s + 2];
    float r = sqrtf(dx * dx + dy * dy + dz * dz);
    float ri = 1.0f / fmaxf(r, EPSF);
    ecs[t] = make_float4(r, dx * ri, dy * ri, dz * ri);
    float we = w[e];
    wsrt[t] = we;
    srcs[t] = s;
    double wd = (double)we, rd = (double)r;
    lw += wd; lr += rd; lww += wd * wd; lrr += rd * rd; lwr += wd * rd;
  }
#pragma unroll
  for (int d = 32; d >= 1; d >>= 1) {
    lw += __shfl_xor(lw, d);
    lr += __shfl_xor(lr, d);
    lww += __shfl_xor(lww, d);
    lrr += __shfl_xor(lrr, d);
    lwr += __shfl_xor(lwr, d);
  }
  int wid = threadIdx.x >> 6;
  if ((threadIdx.x & 63) == 0) {
    sred[0 * 4 + wid] = lw;
    sred[1 * 4 + wid] = lr;
    sred[2 * 4 + wid] = lww;
    sred[3 * 4 + wid] = lrr;
    sred[4 * 4 + wid] = lwr;
  }
  __syncthreads();
  if (threadIdx.x < 5) {
    double v = sred[threadIdx.x * 4 + 0] + sred[threadIdx.x * 4 + 1]
             + sred[threadIdx.x * 4 + 2] + sred[threadIdx.x * 4 + 3];
    atomAddD((double*)ws + threadIdx.x * 8, v);
  }
}

// ---- fin1 ----
__global__ void k_fin1(const float* __restrict__ rW1, const float* __restrict__ rb1,
                       const float* __restrict__ rg1, const float* __restrict__ rbe1,
                       float* __restrict__ ws) {
  int t = threadIdx.x;
  int k = t >> 5, j = t & 31;
  const double* s1 = (const double*)ws;
  double Sw = s1[0], Sr = s1[8], Sww = s1[16], Srr = s1[24], Swr = s1[32];
  const double inv = 1.0 / (double)NE;
  double W0 = (double)rW1[k * 64 + j], W1 = (double)rW1[k * 64 + 32 + j];
  double b = (double)rb1[k * 32 + j];
  double mlin = (Sw * W0 + Sr * W1) * inv;
  double mu = mlin + b;
  double ex2 = (Sww * W0 * W0 + Srr * W1 * W1 + 2.0 * Swr * W0 * W1) * inv
             + 2.0 * b * mlin + b * b;
  double var = ex2 - mu * mu;
  double a = (double)rg1[k * 32 + j] / sqrt(var + 1e-5);
  ws[OFF_FW1A + t] = (float)(W0 * a);
  ws[OFF_FW1B + t] = (float)(W1 * a);
  ws[OFF_FC1 + t] = (float)((double)rbe1[k * 32 + j] - mlin * a);
}

// ---- NEW: k_mlp — compute all 6 nets' pre-activations P = b2 + h@W2raw ----
__global__ __launch_bounds__(256) void k_mlp(
    const float* __restrict__ rW2, const float* __restrict__ rb2,
    float* __restrict__ ws) {
  __shared__ __align__(16) float sW1a[192], sW1b[192], sc1[192], sB2[192];
  __shared__ __align__(16) float sW2T6[6144];  // [k][j][i]
  int tid = threadIdx.x;
  if (tid < 192) {
    sW1a[tid] = ws[OFF_FW1A + tid];
    sW1b[tid] = ws[OFF_FW1B + tid];
    sc1[tid] = ws[OFF_FC1 + tid];
    sB2[tid] = rb2[tid];
  }
  for (int t2 = tid; t2 < 6144; t2 += 256) {
    int k = t2 >> 10, rem = t2 & 1023;
    int j = rem >> 5, i = rem & 31;
    sW2T6[t2] = rW2[k * 1024 + i * 32 + j];
  }
  __syncthreads();

  const float* wsrt = ws + OFF_WSRT;
  const float4* ecs = (const float4*)(ws + OFF_ECS);
  int t = blockIdx.x * blockDim.x + tid;
  if (t >= NE) return;
  float we = wsrt[t];
  float r = ecs[t].x;

#pragma unroll 1
  for (int k = 0; k < 6; ++k) {
    const float* a1 = sW1a + k * 32;
    const float* b1 = sW1b + k * 32;
    const float* c1 = sc1 + k * 32;
    const float* b2 = sB2 + k * 32;
    const float* w2 = sW2T6 + k * 1024;
    float h[MID];
#pragma unroll
    for (int j4 = 0; j4 < 8; ++j4) {
      float4 av = ((const float4*)a1)[j4];
      float4 bv = ((const float4*)b1)[j4];
      float4 cv = ((const float4*)c1)[j4];
      h[4 * j4 + 0] = fmaxf(fmaf(we, av.x, fmaf(r, bv.x, cv.x)), 0.0f);
      h[4 * j4 + 1] = fmaxf(fmaf(we, av.y, fmaf(r, bv.y, cv.y)), 0.0f);
      h[4 * j4 + 2] = fmaxf(fmaf(we, av.z, fmaf(r, bv.z, cv.z)), 0.0f);
      h[4 * j4 + 3] = fmaxf(fmaf(we, av.w, fmaf(r, bv.w, cv.w)), 0.0f);
    }
    SCHED_FENCE();
    float4* pp = (float4*)(ws + OFF_PRE) + (size_t)k * (NE * 8) + (size_t)t * 8;
#pragma unroll
    for (int jg = 0; jg < 8; ++jg) {
      float q0, q1, q2, q3;
      {
        float acc = b2[jg * 4 + 0];
        const float4* wp = (const float4*)(w2 + (jg * 4 + 0) * 32);
#pragma unroll
        for (int i4 = 0; i4 < 8; ++i4) {
          float4 wv = wp[i4];
          acc = fmaf(h[4 * i4 + 0], wv.x, acc);
          acc = fmaf(h[4 * i4 + 1], wv.y, acc);
          acc = fmaf(h[4 * i4 + 2], wv.z, acc);
          acc = fmaf(h[4 * i4 + 3], wv.w, acc);
        }
        q0 = acc;
      }
      {
        float acc = b2[jg * 4 + 1];
        const float4* wp = (const float4*)(w2 + (jg * 4 + 1) * 32);
#pragma unroll
        for (int i4 = 0; i4 < 8; ++i4) {
          float4 wv = wp[i4];
          acc = fmaf(h[4 * i4 + 0], wv.x, acc);
          acc = fmaf(h[4 * i4 + 1], wv.y, acc);
          acc = fmaf(h[4 * i4 + 2], wv.z, acc);
          acc = fmaf(h[4 * i4 + 3], wv.w, acc);
        }
        q1 = acc;
      }
      {
        float acc = b2[jg * 4 + 2];
        const float4* wp = (const float4*)(w2 + (jg * 4 + 2) * 32);
#pragma unroll
        for (int i4 = 0; i4 < 8; ++i4) {
          float4 wv = wp[i4];
          acc = fmaf(h[4 * i4 + 0], wv.x, acc);
          acc = fmaf(h[4 * i4 + 1], wv.y, acc);
          acc = fmaf(h[4 * i4 + 2], wv.z, acc);
          acc = fmaf(h[4 * i4 + 3], wv.w, acc);
        }
        q2 = acc;
      }
      {
        float acc = b2[jg * 4 + 3];
        const float4* wp = (const float4*)(w2 + (jg * 4 + 3) * 32);
#pragma unroll
        for (int i4 = 0; i4 < 8; ++i4) {
          float4 wv = wp[i4];
          acc = fmaf(h[4 * i4 + 0], wv.x, acc);
          acc = fmaf(h[4 * i4 + 1], wv.y, acc);
          acc = fmaf(h[4 * i4 + 2], wv.z, acc);
          acc = fmaf(h[4 * i4 + 3], wv.w, acc);
        }
        q3 = acc;
      }
      pp[jg] = make_float4(q0, q1, q2, q3);
      SCHED_FENCE();
    }
  }
}

// ---- NEW: stats over stored P (memory-bound) ----
__global__ __launch_bounds__(256) void k_stats2P(float* __restrict__ ws) {
  const int k = blockIdx.y;
  __shared__ float sredf[2][32][4];
  int tid = threadIdx.x;
  float ls[32], lq[32];
#pragma unroll
  for (int j = 0; j < 32; ++j) { ls[j] = 0.0f; lq[j] = 0.0f; }
  const float4* Pk = (const float4*)(ws + OFF_PRE) + (size_t)k * (NE * 8);
  for (int t = blockIdx.x * blockDim.x + tid; t < NE;
       t += gridDim.x * blockDim.x) {
    const float4* pp = Pk + (size_t)t * 8;
#pragma unroll
    for (int j4 = 0; j4 < 8; ++j4) {
      float4 v = pp[j4];
      ls[4 * j4 + 0] += v.x; lq[4 * j4 + 0] = fmaf(v.x, v.x, lq[4 * j4 + 0]);
      ls[4 * j4 + 1] += v.y; lq[4 * j4 + 1] = fmaf(v.y, v.y, lq[4 * j4 + 1]);
      ls[4 * j4 + 2] += v.z; lq[4 * j4 + 2] = fmaf(v.z, v.z, lq[4 * j4 + 2]);
      ls[4 * j4 + 3] += v.w; lq[4 * j4 + 3] = fmaf(v.w, v.w, lq[4 * j4 + 3]);
    }
  }
  int wid = tid >> 6;
#pragma unroll
  for (int j = 0; j < 32; ++j) {
    float v1 = ls[j], v2 = lq[j];
#pragma unroll
    for (int d = 32; d >= 1; d >>= 1) {
      v1 += __shfl_xor(v1, d);
      v2 += __shfl_xor(v2, d);
    }
    if ((tid & 63) == 0) {
      sredf[0][j][wid] = v1;
      sredf[1][j][wid] = v2;
    }
  }
  __syncthreads();
  if (tid < 64) {
    int j = tid & 31, which = tid >> 5;
    float v = sredf[which][j][0] + sredf[which][j][1]
            + sredf[which][j][2] + sredf[which][j][3];
    double* s2 = (double*)(ws + 80);
    atomAddD(s2 + k * 64 + which * 32 + j, (double)v);
  }
}

// ---- OLD stats2: 2 edges/thread, z=2, float4 LDS weight reads ----
__global__ __launch_bounds__(256) void k_stats2(
    const float* __restrict__ rW2, const float* __restrict__ rb2,
    float* __restrict__ ws) {
  const int k = blockIdx.y;
  const int j0 = blockIdx.z * 16;
  __shared__ __align__(16) float sW1a[32], sW1b[32], sc1[32];
  __shared__ __align__(16) float sW2c[512];
  __shared__ float sb2[16];
  __shared__ float sredf[2][16][4];
  int tid = threadIdx.x;
  if (tid < 32) {
    sW1a[tid] = ws[OFF_FW1A + k * 32 + tid];
    sW1b[tid] = ws[OFF_FW1B + k * 32 + tid];
    sc1[tid] = ws[OFF_FC1 + k * 32 + tid];
  }
  if (tid < 16) sb2[tid] = rb2[k * 32 + j0 + tid];
  for (int t = tid; t < 512; t += 256) {
    int jj = t >> 5, i = t & 31;
    sW2c[t] = rW2[k * 1024 + i * 32 + j0 + jj];
  }
  __syncthreads();
  const float4* ecs = (const float4*)(ws + OFF_ECS);
  const float* wsrt = ws + OFF_WSRT;
  float lsum[16], lsq[16];
#pragma unroll
  for (int jj = 0; jj < 16; ++jj) { lsum[jj] = 0.0f; lsq[jj] = 0.0f; }
  const int NP = NE / 2;
  for (int p = blockIdx.x * blockDim.x + tid; p < NP;
       p += gridDim.x * blockDim.x) {
    int e0 = 2 * p;
    float r0 = ecs[e0].x, r1 = ecs[e0 + 1].x;
    float w0 = wsrt[e0], w1 = wsrt[e0 + 1];
    float h0[MID], h1[MID];
#pragma unroll
    for (int j4 = 0; j4 < 8; ++j4) {
      float4 av = ((const float4*)sW1a)[j4];
      float4 bv = ((const float4*)sW1b)[j4];
      float4 cv = ((const float4*)sc1)[j4];
      h0[4 * j4 + 0] = fmaxf(fmaf(w0, av.x, fmaf(r0, bv.x, cv.x)), 0.0f);
      h1[4 * j4 + 0] = fmaxf(fmaf(w1, av.x, fmaf(r1, bv.x, cv.x)), 0.0f);
      h0[4 * j4 + 1] = fmaxf(fmaf(w0, av.y, fmaf(r0, bv.y, cv.y)), 0.0f);
      h1[4 * j4 + 1] = fmaxf(fmaf(w1, av.y, fmaf(r1, bv.y, cv.y)), 0.0f);
      h0[4 * j4 + 2] = fmaxf(fmaf(w0, av.z, fmaf(r0, bv.z, cv.z)), 0.0f);
      h1[4 * j4 + 2] = fmaxf(fmaf(w1, av.z, fmaf(r1, bv.z, cv.z)), 0.0f);
      h0[4 * j4 + 3] = fmaxf(fmaf(w0, av.w, fmaf(r0, bv.w, cv.w)), 0.0f);
      h1[4 * j4 + 3] = fmaxf(fmaf(w1, av.w, fmaf(r1, bv.w, cv.w)), 0.0f);
    }
    SCHED_FENCE();
#pragma unroll
    for (int jg = 0; jg < 4; ++jg) {
#pragma unroll
      for (int jq = 0; jq < 4; ++jq) {
        const int jj = jg * 4 + jq;
        float aE0 = sb2[jj], aE1 = sb2[jj];
        const float4* wp = (const float4*)(sW2c + jj * 32);
#pragma unroll
        for (int i4 = 0; i4 < 8; ++i4) {
          float4 wv = wp[i4];
          aE0 = fmaf(h0[4 * i4 + 0], wv.x, aE0);
          aE1 = fmaf(h1[4 * i4 + 0], wv.x, aE1);
          aE0 = fmaf(h0[4 * i4 + 1], wv.y, aE0);
          aE1 = fmaf(h1[4 * i4 + 1], wv.y, aE1);
          aE0 = fmaf(h0[4 * i4 + 2], wv.z, aE0);
          aE1 = fmaf(h1[4 * i4 + 2], wv.z, aE1);
          aE0 = fmaf(h0[4 * i4 + 3], wv.w, aE0);
          aE1 = fmaf(h1[4 * i4 + 3], wv.w, aE1);
        }
        lsum[jj] += aE0 + aE1;
        lsq[jj] = fmaf(aE0, aE0, fmaf(aE1, aE1, lsq[jj]));
      }
      SCHED_FENCE();
    }
  }
  int wid = tid >> 6;
#pragma unroll
  for (int jj = 0; jj < 16; ++jj) {
    float v1 = lsum[jj], v2 = lsq[jj];
#pragma unroll
    for (int d = 32; d >= 1; d >>= 1) {
      v1 += __shfl_xor(v1, d);
      v2 += __shfl_xor(v2, d);
    }
    if ((tid & 63) == 0) {
      sredf[0][jj][wid] = v1;
      sredf[1][jj][wid] = v2;
    }
  }
  __syncthreads();
  if (tid < 32) {
    int jj = tid & 15, which = tid >> 4;
    float v = sredf[which][jj][0] + sredf[which][jj][1]
            + sredf[which][jj][2] + sredf[which][jj][3];
    double* s2 = (double*)(ws + 80);
    atomAddD(s2 + k * 64 + which * 32 + j0 + jj, (double)v);
  }
}

// fin2: writes BN2A (a), FC2 (old fold) and CC2 = be - mu*a (new path)
__global__ void k_fin2(const float* __restrict__ rb2,
                       const float* __restrict__ rg2, const float* __restrict__ rbe2,
                       float* __restrict__ ws) {
  int t = threadIdx.x;
  int k = t >> 5, j = t & 31;
  const double* s2 = (const double*)(ws + 80);
  const double inv = 1.0 / (double)NE;
  double mu = s2[k * 64 + j] * inv;
  double ex2 = s2[k * 64 + 32 + j] * inv;
  double var = ex2 - mu * mu;
  double a = (double)rg2[t] / sqrt(var + 1e-5);
  ws[OFF_BN2A + t] = (float)a;
  ws[OFF_FC2 + t] = (float)((double)rbe2[t] + ((double)rb2[t] - mu) * a);
  ws[OFF_CC2 + t] = (float)((double)rbe2[t] - mu * a);
}

__global__ __launch_bounds__(256) void k_fold2(const float* __restrict__ rW2,
                                               float* __restrict__ ws) {
  int idx = blockIdx.x * blockDim.x + threadIdx.x;
  if (idx >= 6144) return;
  int k = idx >> 10, rem = idx & 1023;
  int j = rem >> 5, i = rem & 31;
  ws[OFF_FW2T + idx] = rW2[k * 1024 + i * 32 + j] * ws[OFF_BN2A + k * 32 + j];
}

// ---- NEW A0: P-based (nets 0,2) ----
__global__ __launch_bounds__(256) void k_passA0P(
    const float* __restrict__ cI, const float* __restrict__ vI,
    const float* __restrict__ w00, const float* __restrict__ b00,
    const float* __restrict__ w10, const float* __restrict__ b10,
    float* __restrict__ ws) {
  __shared__ __align__(16) float sA2a[32], sCCa[32], sA2b[32], sCCb[32];
  __shared__ __align__(16) float sP00[512], sP10[512];
  __shared__ float sB00[16], sB10[16];
  int tid = threadIdx.x;
  if (tid < 32) {
    sA2a[tid] = ws[OFF_BN2A + tid];        // net 0
    sCCa[tid] = ws[OFF_CC2 + tid];
    sA2b[tid] = ws[OFF_BN2A + 64 + tid];   // net 2
    sCCb[tid] = ws[OFF_CC2 + 64 + tid];
  }
  for (int t2 = tid; t2 < 512; t2 += 256) {
    int i = t2 >> 4, co = t2 & 15;
    sP00[co * 32 + i] = w00[t2];
    sP10[co * 32 + i] = w10[t2];
  }
  if (tid < 16) { sB00[tid] = b00[tid]; sB10[tid] = b10[tid]; }
  __syncthreads();

  const int* srcs = (const int*)ws + OFF_SRCS;
  const float4* ecs = (const float4*)(ws + OFF_ECS);
  int t = blockIdx.x * blockDim.x + tid;
  if (t >= NE) return;
  int s = srcs[t];
  float4 E = ecs[t];
  float cs = cI[s];
  float v0 = vI[3 * s + 0], v1 = vI[3 * s + 1], v2 = vI[3 * s + 2];
  float dY1v = Y1C * (E.z * v0 + E.w * v1 + E.y * v2);

  float H[MID], m0[CDIM];
  loadH_P((const float4*)(ws + OFF_PRE) + (size_t)t * 8, sA2a, sCCa, H);
  float f0 = Y0C * cs;
#pragma unroll
  for (int cg = 0; cg < 4; ++cg) {
#pragma unroll
    for (int cq = 0; cq < 4; ++cq) {
      const int co = cg * 4 + cq;
      float a = sB00[co];
      const float4* wp = (const float4*)(sP00 + co * 32);
#pragma unroll
      for (int i4 = 0; i4 < 8; ++i4) {
        float4 wv = wp[i4];
        a = fmaf(H[4 * i4 + 0], wv.x, a);
        a = fmaf(H[4 * i4 + 1], wv.y, a);
        a = fmaf(H[4 * i4 + 2], wv.z, a);
        a = fmaf(H[4 * i4 + 3], wv.w, a);
      }
      m0[co] = a * f0;
    }
    SCHED_FENCE();
  }
  loadH_P((const float4*)(ws + OFF_PRE) + (size_t)2 * (NE * 8) + (size_t)t * 8,
          sA2b, sCCb, H);
#pragma unroll
  for (int cg = 0; cg < 4; ++cg) {
#pragma unroll
    for (int cq = 0; cq < 4; ++cq) {
      const int co = cg * 4 + cq;
      float a = sB10[co];
      const float4* wp = (const float4*)(sP10 + co * 32);
#pragma unroll
      for (int i4 = 0; i4 < 8; ++i4) {
        float4 wv = wp[i4];
        a = fmaf(H[4 * i4 + 0], wv.x, a);
        a = fmaf(H[4 * i4 + 1], wv.y, a);
        a = fmaf(H[4 * i4 + 2], wv.z, a);
        a = fmaf(H[4 * i4 + 3], wv.w, a);
      }
      m0[co] = fmaf(a, dY1v, m0[co]);
    }
    SCHED_FENCE();
  }
  float4* mp = (float4*)(ws + OFF_MSGA0) + t * 4;
#pragma unroll
  for (int q = 0; q < 4; ++q)
    mp[q] = make_float4(m0[4 * q], m0[4 * q + 1], m0[4 * q + 2], m0[4 * q + 3]);
}

// ---- NEW A1: P-based (nets 1,3), group-major msgA1 ----
__global__ __launch_bounds__(256) void k_passA1P(
    const float* __restrict__ cI, const float* __restrict__ vI,
    const float* __restrict__ w01, const float* __restrict__ b01,
    const float* __restrict__ w11, const float* __restrict__ b11,
    float* __restrict__ ws) {
  __shared__ __align__(16) float sA2a[32], sCCa[32], sA2b[32], sCCb[32];
  __shared__ __align__(16) float sP01[512], sP11[1536];
  __shared__ float sB01[16], sB11[48];
  int tid = threadIdx.x;
  if (tid < 32) {
    sA2a[tid] = ws[OFF_BN2A + 32 + tid];   // net 1
    sCCa[tid] = ws[OFF_CC2 + 32 + tid];
    sA2b[tid] = ws[OFF_BN2A + 96 + tid];   // net 3
    sCCb[tid] = ws[OFF_CC2 + 96 + tid];
  }
  for (int t2 = tid; t2 < 512; t2 += 256) {
    int i = t2 >> 4, co = t2 & 15;
    sP01[co * 32 + i] = w01[t2];
  }
  for (int t2 = tid; t2 < 1536; t2 += 256) {
    int i = t2 / 48, c = t2 - i * 48;
    sP11[c * 32 + i] = w11[t2];
  }
  if (tid < 16) sB01[tid] = b01[tid];
  if (tid < 48) sB11[tid] = b11[tid];
  __syncthreads();

  const int* srcs = (const int*)ws + OFF_SRCS;
  const float4* ecs = (const float4*)(ws + OFF_ECS);
  int t = blockIdx.x * blockDim.x + tid;
  if (t >= NE) return;
  int s = srcs[t];
  float4 E = ecs[t];
  float cs = cI[s];

  float H[MID];
  float ra[16];
  loadH_P((const float4*)(ws + OFF_PRE) + (size_t)1 * (NE * 8) + (size_t)t * 8,
          sA2a, sCCa, H);
#pragma unroll
  for (int cg = 0; cg < 4; ++cg) {
#pragma unroll
    for (int cq = 0; cq < 4; ++cq) {
      const int co = cg * 4 + cq;
      float a = sB01[co];
      const float4* wp = (const float4*)(sP01 + co * 32);
#pragma unroll
      for (int i4 = 0; i4 < 8; ++i4) {
        float4 wv = wp[i4];
        a = fmaf(H[4 * i4 + 0], wv.x, a);
        a = fmaf(H[4 * i4 + 1], wv.y, a);
        a = fmaf(H[4 * i4 + 2], wv.z, a);
        a = fmaf(H[4 * i4 + 3], wv.w, a);
      }
      ra[co] = a;
    }
    SCHED_FENCE();
  }
  loadH_P((const float4*)(ws + OFF_PRE) + (size_t)3 * (NE * 8) + (size_t)t * 8,
          sA2b, sCCb, H);
  float y10 = Y1C * E.z, y11 = Y1C * E.w, y12 = Y1C * E.y;
  float KV[3][3];
  {
    float ux = E.y, uy = E.z, uz = E.w;
    float y20 = Y2C1 * ux * uy, y21 = Y2C1 * uy * uz;
    float y22 = Y2C2 * (3.0f * uz * uz - 1.0f);
    float y23 = Y2C1 * ux * uz, y24 = Y2C3 * (ux * ux - uy * uy);
    float S00 = -S6C * y22 - S2C * y24;
    float S11 = 2.0f * S6C * y22;
    float S22 = -S6C * y22 + S2C * y24;
    float S01 = S2C * y21, S02 = S2C * y20, S12 = S2C * y23;
    float v0 = vI[3 * s + 0], v1 = vI[3 * s + 1], v2 = vI[3 * s + 2];
    KV[0][0] = K0C * v0; KV[0][1] = K0C * v1; KV[0][2] = K0C * v2;
    KV[1][0] = S2C * (y12 * v1 - y11 * v2);
    KV[1][1] = S2C * (y10 * v2 - y12 * v0);
    KV[1][2] = S2C * (y11 * v0 - y10 * v1);
    KV[2][0] = S00 * v0 + S01 * v1 + S02 * v2;
    KV[2][1] = S01 * v0 + S11 * v1 + S12 * v2;
    KV[2][2] = S02 * v0 + S12 * v1 + S22 * v2;
  }
  float cy0 = cs * y10, cy1 = cs * y11, cy2 = cs * y12;
#pragma unroll 1
  for (int g = 0; g < 4; ++g) {
    float a[12];
#pragma unroll
    for (int q = 0; q < 4; ++q) {
      int co = g * 4 + q;
      float R0 = sB11[co * 3 + 0], R1 = sB11[co * 3 + 1], R2 = sB11[co * 3 + 2];
      const float4* p0 = (const float4*)(sP11 + (co * 3 + 0) * 32);
      const float4* p1 = (const float4*)(sP11 + (co * 3 + 1) * 32);
      const float4* p2 = (const float4*)(sP11 + (co * 3 + 2) * 32);
#pragma unroll
      for (int i4 = 0; i4 < 8; ++i4) {
        float4 w0v = p0[i4], w1v = p1[i4], w2v = p2[i4];
        float h0 = H[4 * i4 + 0], h1 = H[4 * i4 + 1];
        float h2 = H[4 * i4 + 2], h3 = H[4 * i4 + 3];
        R0 = fmaf(h0, w0v.x, R0); R1 = fmaf(h0, w1v.x, R1); R2 = fmaf(h0, w2v.x, R2);
        R0 = fmaf(h1, w0v.y, R0); R1 = fmaf(h1, w1v.y, R1); R2 = fmaf(h1, w2v.y, R2);
        R0 = fmaf(h2, w0v.z, R0); R1 = fmaf(h2, w1v.z, R1); R2 = fmaf(h2, w2v.z, R2);
        R0 = fmaf(h3, w0v.w, R0); R1 = fmaf(h3, w1v.w, R1); R2 = fmaf(h3, w2v.w, R2);
      }
      float r_ = ra[co];
      a[q * 3 + 0] = fmaf(r_, cy0, R0 * KV[0][0] + R1 * KV[1][0] + R2 * KV[2][0]);
      a[q * 3 + 1] = fmaf(r_, cy1, R0 * KV[0][1] + R1 * KV[1][1] + R2 * KV[2][1]);
      a[q * 3 + 2] = fmaf(r_, cy2, R0 * KV[0][2] + R1 * KV[1][2] + R2 * KV[2][2]);
    }
    float4* mp = (float4*)(ws + OFF_MSGA1 + g * (NE * 12)) + t * 3;
    mp[0] = make_float4(a[0], a[1], a[2], a[3]);
    mp[1] = make_float4(a[4], a[5], a[6], a[7]);
    mp[2] = make_float4(a[8], a[9], a[10], a[11]);
    SCHED_FENCE();
  }
}

// ---- OLD A0 (1-edge) ----
__global__ __launch_bounds__(256) void k_passA0(
    const float* __restrict__ cI, const float* __restrict__ vI,
    const float* __restrict__ w00, const float* __restrict__ b00,
    const float* __restrict__ w10, const float* __restrict__ b10,
    float* __restrict__ ws) {
  __shared__ __align__(16) float sW1a[64], sW1b[64], sc1[64], sc2[64];
  __shared__ __align__(16) float sW2T[2048];
  __shared__ __align__(16) float sP00[512], sP10[512];
  __shared__ float sB00[16], sB10[16];
  int tid = threadIdx.x;
  if (tid < 32) {
    sW1a[tid] = ws[OFF_FW1A + tid];       sW1a[32 + tid] = ws[OFF_FW1A + 64 + tid];
    sW1b[tid] = ws[OFF_FW1B + tid];       sW1b[32 + tid] = ws[OFF_FW1B + 64 + tid];
    sc1[tid]  = ws[OFF_FC1 + tid];        sc1[32 + tid]  = ws[OFF_FC1 + 64 + tid];
    sc2[tid]  = ws[OFF_FC2 + tid];        sc2[32 + tid]  = ws[OFF_FC2 + 64 + tid];
  }
  for (int t = tid; t < 2048; t += 256) {
    sW2T[t] = ws[OFF_FW2T + ((t < 1024) ? t : (1024 + t))];
  }
  for (int t = tid; t < 512; t += 256) {
    int i = t >> 4, co = t & 15;
    sP00[co * 32 + i] = w00[t];
    sP10[co * 32 + i] = w10[t];
  }
  if (tid < 16) { sB00[tid] = b00[tid]; sB10[tid] = b10[tid]; }
  __syncthreads();

  const int* srcs = (const int*)ws + OFF_SRCS;
  const float* wsrt = ws + OFF_WSRT;
  const float4* ecs = (const float4*)(ws + OFF_ECS);
  int t = blockIdx.x * blockDim.x + tid;
  if (t >= NE) return;
  int s = srcs[t];
  float4 E = ecs[t];
  float we = wsrt[t];
  float cs = cI[s];
  float v0 = vI[3 * s + 0], v1 = vI[3 * s + 1], v2 = vI[3 * s + 2];
  float dY1v = Y1C * (E.z * v0 + E.w * v1 + E.y * v2);

  float H[MID], m0[CDIM];
  mlpH_lds(sW1a, sW1b, sc1, sc2, sW2T, we, E.x, H);
  float f0 = Y0C * cs;
#pragma unroll
  for (int cg = 0; cg < 4; ++cg) {
#pragma unroll
    for (int cq = 0; cq < 4; ++cq) {
      const int co = cg * 4 + cq;
      float a = sB00[co];
      const float4* wp = (const float4*)(sP00 + co * 32);
#pragma unroll
      for (int i4 = 0; i4 < 8; ++i4) {
        float4 wv = wp[i4];
        a = fmaf(H[4 * i4 + 0], wv.x, a);
        a = fmaf(H[4 * i4 + 1], wv.y, a);
        a = fmaf(H[4 * i4 + 2], wv.z, a);
        a = fmaf(H[4 * i4 + 3], wv.w, a);
      }
      m0[co] = a * f0;
    }
    SCHED_FENCE();
  }
  mlpH_lds(sW1a + 32, sW1b + 32, sc1 + 32, sc2 + 32, sW2T + 1024, we, E.x, H);
#pragma unroll
  for (int cg = 0; cg < 4; ++cg) {
#pragma unroll
    for (int cq = 0; cq < 4; ++cq) {
      const int co = cg * 4 + cq;
      float a = sB10[co];
      const float4* wp = (const float4*)(sP10 + co * 32);
#pragma unroll
      for (int i4 = 0; i4 < 8; ++i4) {
        float4 wv = wp[i4];
        a = fmaf(H[4 * i4 + 0], wv.x, a);
        a = fmaf(H[4 * i4 + 1], wv.y, a);
        a = fmaf(H[4 * i4 + 2], wv.z, a);
        a = fmaf(H[4 * i4 + 3], wv.w, a);
      }
      m0[co] = fmaf(a, dY1v, m0[co]);
    }
    SCHED_FENCE();
  }
  float4* mp = (float4*)(ws + OFF_MSGA0) + t * 4;
#pragma unroll
  for (int q = 0; q < 4; ++q)
    mp[q] = make_float4(m0[4 * q], m0[4 * q + 1], m0[4 * q + 2], m0[4 * q + 3]);
}

// ---- OLD A1 (1-edge) ----
__global__ __launch_bounds__(256) void k_passA1(
    const float* __restrict__ cI, const float* __restrict__ vI,
    const float* __restrict__ w01, const float* __restrict__ b01,
    const float* __restrict__ w11, const float* __restrict__ b11,
    float* __restrict__ ws) {
  __shared__ __align__(16) float sW1a[64], sW1b[64], sc1[64], sc2[64];
  __shared__ __align__(16) float sW2T[2048];
  __shared__ __align__(16) float sP01[512], sP11[1536];
  __shared__ float sB01[16], sB11[48];
  int tid = threadIdx.x;
  if (tid < 32) {
    sW1a[tid] = ws[OFF_FW1A + 32 + tid];  sW1a[32 + tid] = ws[OFF_FW1A + 96 + tid];
    sW1b[tid] = ws[OFF_FW1B + 32 + tid];  sW1b[32 + tid] = ws[OFF_FW1B + 96 + tid];
    sc1[tid]  = ws[OFF_FC1 + 32 + tid];   sc1[32 + tid]  = ws[OFF_FC1 + 96 + tid];
    sc2[tid]  = ws[OFF_FC2 + 32 + tid];   sc2[32 + tid]  = ws[OFF_FC2 + 96 + tid];
  }
  for (int t = tid; t < 1024; t += 256) {
    sW2T[t] = ws[OFF_FW2T + 1024 + t];
    sW2T[1024 + t] = ws[OFF_FW2T + 3072 + t];
  }
  for (int t = tid; t < 512; t += 256) {
    int i = t >> 4, co = t & 15;
    sP01[co * 32 + i] = w01[t];
  }
  for (int t = tid; t < 1536; t += 256) {
    int i = t / 48, c = t - i * 48;
    sP11[c * 32 + i] = w11[t];
  }
  if (tid < 16) sB01[tid] = b01[tid];
  if (tid < 48) sB11[tid] = b11[tid];
  __syncthreads();

  const int* srcs = (const int*)ws + OFF_SRCS;
  const float* wsrt = ws + OFF_WSRT;
  const float4* ecs = (const float4*)(ws + OFF_ECS);
  int t = blockIdx.x * blockDim.x + tid;
  if (t >= NE) return;
  int s = srcs[t];
  float4 E = ecs[t];
  float we = wsrt[t];
  float cs = cI[s];

  float H[MID];
  float ra[16];
  mlpH_lds(sW1a, sW1b, sc1, sc2, sW2T, we, E.x, H);
#pragma unroll
  for (int cg = 0; cg < 4; ++cg) {
#pragma unroll
    for (int cq = 0; cq < 4; ++cq) {
      const int co = cg * 4 + cq;
      float a = sB01[co];
      const float4* wp = (const float4*)(sP01 + co * 32);
#pragma unroll
      for (int i4 = 0; i4 < 8; ++i4) {
        float4 wv = wp[i4];
        a = fmaf(H[4 * i4 + 0], wv.x, a);
        a = fmaf(H[4 * i4 + 1], wv.y, a);
        a = fmaf(H[4 * i4 + 2], wv.z, a);
        a = fmaf(H[4 * i4 + 3], wv.w, a);
      }
      ra[co] = a;
    }
    SCHED_FENCE();
  }
  mlpH_lds(sW1a + 32, sW1b + 32, sc1 + 32, sc2 + 32, sW2T + 1024, we, E.x, H);
  float y10 = Y1C * E.z, y11 = Y1C * E.w, y12 = Y1C * E.y;
  float KV[3][3];
  {
    float ux = E.y, uy = E.z, uz = E.w;
    float y20 = Y2C1 * ux * uy, y21 = Y2C1 * uy * uz;
    float y22 = Y2C2 * (3.0f * uz * uz - 1.0f);
    float y23 = Y2C1 * ux * uz, y24 = Y2C3 * (ux * ux - uy * uy);
    float S00 = -S6C * y22 - S2C * y24;
    float S11 = 2.0f * S6C * y22;
    float S22 = -S6C * y22 + S2C * y24;
    float S01 = S2C * y21, S02 = S2C * y20, S12 = S2C * y23;
    float v0 = vI[3 * s + 0], v1 = vI[3 * s + 1], v2 = vI[3 * s + 2];
    KV[0][0] = K0C * v0; KV[0][1] = K0C * v1; KV[0][2] = K0C * v2;
    KV[1][0] = S2C * (y12 * v1 - y11 * v2);
    KV[1][1] = S2C * (y10 * v2 - y12 * v0);
    KV[1][2] = S2C * (y11 * v0 - y10 * v1);
    KV[2][0] = S00 * v0 + S01 * v1 + S02 * v2;
    KV[2][1] = S01 * v0 + S11 * v1 + S12 * v2;
    KV[2][2] = S02 * v0 + S12 * v1 + S22 * v2;
  }
  float cy0 = cs * y10, cy1 = cs * y11, cy2 = cs * y12;
#pragma unroll 1
  for (int g = 0; g < 4; ++g) {
    float a[12];
#pragma unroll
    for (int q = 0; q < 4; ++q) {
      int co = g * 4 + q;
      float R0 = sB11[co * 3 + 0], R1 = sB11[co * 3 + 1], R2 = sB11[co * 3 + 2];
      const float4* p0 = (const float4*)(sP11 + (co * 3 + 0) * 32);
      const float4* p1 = (const float4*)(sP11 + (co * 3 + 1) * 32);
      const float4* p2 = (const float4*)(sP11 + (co * 3 + 2) * 32);
#pragma unroll
      for (int i4 = 0; i4 < 8; ++i4) {
        float4 w0v = p0[i4], w1v = p1[i4], w2v = p2[i4];
        float h0 = H[4 * i4 + 0], h1 = H[4 * i4 + 1];
        float h2 = H[4 * i4 + 2], h3 = H[4 * i4 + 3];
        R0 = fmaf(h0, w0v.x, R0); R1 = fmaf(h0, w1v.x, R1); R2 = fmaf(h0, w2v.x, R2);
        R0 = fmaf(h1, w0v.y, R0); R1 = fmaf(h1, w1v.y, R1); R2 = fmaf(h1, w2v.y, R2);
        R0 = fmaf(h2, w0v.z, R0); R1 = fmaf(h2, w1v.z, R1); R2 = fmaf(h2, w2v.z, R2);
        R0 = fmaf(h3, w0v.w, R0); R1 = fmaf(h3, w1v.w, R1); R2 = fmaf(h3, w2v.w, R2);
      }
      float r_ = ra[co];
      a[q * 3 + 0] = fmaf(r_, cy0, R0 * KV[0][0] + R1 * KV[1][0] + R2 * KV[2][0]);
      a[q * 3 + 1] = fmaf(r_, cy1, R0 * KV[0][1] + R1 * KV[1][1] + R2 * KV[2][1]);
      a[q * 3 + 2] = fmaf(r_, cy2, R0 * KV[0][2] + R1 * KV[1][2] + R2 * KV[2][2]);
    }
    float4* mp = (float4*)(ws + OFF_MSGA1 + g * (NE * 12)) + t * 3;
    mp[0] = make_float4(a[0], a[1], a[2], a[3]);
    mp[1] = make_float4(a[4], a[5], a[6], a[7]);
    mp[2] = make_float4(a[8], a[9], a[10], a[11]);
    SCHED_FENCE();
  }
}

// ---- nodeA (msgA1 is group-major: g = co>>2, q = co&3) ----
__global__ __launch_bounds__(256) void k_nodeA(
    const float* __restrict__ cI, const float* __restrict__ vI,
    const float* __restrict__ selfA0, const float* __restrict__ selfA1,
    const float* __restrict__ nbias0, const float* __restrict__ nbias1,
    float* __restrict__ ws) {
  int idx = blockIdx.x * blockDim.x + threadIdx.x;
  if (idx >= NN * CDIM) return;
  int n = idx >> 4, co = idx & 15;
  const int* rowptr = (const int*)ws + OFF_ROWPTR;
  int r0 = rowptr[n], r1 = rowptr[n + 1];
  const float* mA0 = ws + OFF_MSGA0;
  const float* mA1 = ws + OFF_MSGA1 + (co >> 2) * (NE * 12) + (co & 3) * 3;
  float x0 = 0.0f, xa = 0.0f, xb = 0.0f, xc = 0.0f;
  for (int row = r0; row < r1; ++row) {
    x0 += mA0[row * 16 + co];
    xa += mA1[row * 12 + 0];
    xb += mA1[row * 12 + 1];
    xc += mA1[row * 12 + 2];
  }
  float dg = (float)(r1 - r0);
  float iv = 1.0f / fmaxf(dg, 1.0f);
  float mk = dg > 0.0f ? 1.0f : 0.0f;
  x0 = x0 * iv + selfA0[co] * cI[n] * mk;
  float n0 = sqrtf(x0 * x0 + 1e-12f);
  ws[OFF_H0N + idx] = fmaxf(n0 + nbias0[co], 0.0f) * (x0 / fmaxf(n0, EPSF));
  xa = xa * iv + selfA1[co] * vI[3 * n + 0] * mk;
  xb = xb * iv + selfA1[co] * vI[3 * n + 1] * mk;
  xc = xc * iv + selfA1[co] * vI[3 * n + 2] * mk;
  float nv = sqrtf(xa * xa + xb * xb + xc * xc + 1e-12f);
  float sc = fmaxf(nv + nbias1[co], 0.0f) / fmaxf(nv, EPSF);
  ws[OFF_H1N + idx * 3 + 0] = xa * sc;
  ws[OFF_H1N + idx * 3 + 1] = xb * sc;
  ws[OFF_H1N + idx * 3 + 2] = xc * sc;
}

// ---- NEW B: P-based, 2-edge paired ----
__global__ __launch_bounds__(256) void k_passBP(
    const float* __restrict__ wb01, const float* __restrict__ bb01,
    const float* __restrict__ wb11, const float* __restrict__ bb11,
    float* __restrict__ ws) {
  __shared__ __align__(16) float sA2a[32], sCCa[32], sA2b[32], sCCb[32];
  __shared__ __align__(16) float sPB01[1024];
  __shared__ __align__(16) float sPB11[3072];
  __shared__ float sBB01[32];
  __shared__ float sBB11[96];
  int tid = threadIdx.x;
  if (tid < 32) {
    sA2a[tid] = ws[OFF_BN2A + 128 + tid];   // net 4
    sCCa[tid] = ws[OFF_CC2 + 128 + tid];
    sA2b[tid] = ws[OFF_BN2A + 160 + tid];   // net 5
    sCCb[tid] = ws[OFF_CC2 + 160 + tid];
  }
  for (int t = tid; t < 1024; t += 256) {
    int i = t >> 5, c = t & 31;
    int o = c >> 4, ci = c & 15;
    sPB01[(ci * 2 + o) * 32 + i] = wb01[t];
  }
  for (int t = tid; t < 3072; t += 256) {
    int i = t / 96, c = t - i * 96;
    int o = c / 48, rem = c - o * 48;
    int ci = rem / 3, f = rem - ci * 3;
    sPB11[(ci * 6 + o * 3 + f) * 32 + i] = wb11[t];
  }
  if (tid < 32) {
    int o = tid >> 4, ci = tid & 15;
    sBB01[ci * 2 + o] = bb01[tid];
  }
  if (tid < 96) {
    int o = tid / 48, rem = tid - o * 48;
    int ci = rem / 3, f = rem - ci * 3;
    sBB11[ci * 6 + o * 3 + f] = bb11[tid];
  }
  __syncthreads();

  const int* srcs = (const int*)ws + OFF_SRCS;
  const float4* ecs = (const float4*)(ws + OFF_ECS);
  const int NP = NE / 2;
  int p = blockIdx.x * blockDim.x + tid;
  if (p >= NP) return;
  {
    int tA = 2 * p, tB = 2 * p + 1;
    int sA = srcs[tA], sB_ = srcs[tB];
    float4 EA = ecs[tA], EB = ecs[tB];

    float HA[MID], HB[MID];
    loadH_P((const float4*)(ws + OFF_PRE) + (size_t)4 * (NE * 8) + (size_t)tA * 8,
            sA2a, sCCa, HA);
    loadH_P((const float4*)(ws + OFF_PRE) + (size_t)4 * (NE * 8) + (size_t)tB * 8,
            sA2a, sCCa, HB);
    const float* h0pA = ws + OFF_H0N + sA * CDIM;
    const float* h0pB = ws + OFF_H0N + sB_ * CDIM;
    float A0A = 0.0f, A1A = 0.0f, A0B = 0.0f, A1B = 0.0f;
#pragma unroll 1
    for (int ci = 0; ci < CDIM; ++ci) {
      float bA = h0pA[ci], bB = h0pB[ci];
      float R0A = sBB01[ci * 2 + 0], R1A = sBB01[ci * 2 + 1];
      float R0B = R0A, R1B = R1A;
      const float4* p0 = (const float4*)(sPB01 + (ci * 2 + 0) * 32);
      const float4* p1 = (const float4*)(sPB01 + (ci * 2 + 1) * 32);
#pragma unroll
      for (int i4 = 0; i4 < 8; ++i4) {
        float4 w0v = p0[i4], w1v = p1[i4];
        float hA0 = HA[4 * i4 + 0], hB0 = HB[4 * i4 + 0];
        float hA1 = HA[4 * i4 + 1], hB1 = HB[4 * i4 + 1];
        float hA2 = HA[4 * i4 + 2], hB2 = HB[4 * i4 + 2];
        float hA3 = HA[4 * i4 + 3], hB3 = HB[4 * i4 + 3];
        R0A = fmaf(hA0, w0v.x, R0A); R0B = fmaf(hB0, w0v.x, R0B);
        R1A = fmaf(hA0, w1v.x, R1A); R1B = fmaf(hB0, w1v.x, R1B);
        R0A = fmaf(hA1, w0v.y, R0A); R0B = fmaf(hB1, w0v.y, R0B);
        R1A = fmaf(hA1, w1v.y, R1A); R1B = fmaf(hB1, w1v.y, R1B);
        R0A = fmaf(hA2, w0v.z, R0A); R0B = fmaf(hB2, w0v.z, R0B);
        R1A = fmaf(hA2, w1v.z, R1A); R1B = fmaf(hB2, w1v.z, R1B);
        R0A = fmaf(hA3, w0v.w, R0A); R0B = fmaf(hB3, w0v.w, R0B);
        R1A = fmaf(hA3, w1v.w, R1A); R1B = fmaf(hB3, w1v.w, R1B);
      }
      A0A = fmaf(R0A, bA, A0A); A1A = fmaf(R1A, bA, A1A);
      A0B = fmaf(R0B, bB, A0B); A1B = fmaf(R1B, bB, A1B);
      SCHED_FENCE();
    }
    loadH_P((const float4*)(ws + OFF_PRE) + (size_t)5 * (NE * 8) + (size_t)tA * 8,
            sA2b, sCCb, HA);
    loadH_P((const float4*)(ws + OFF_PRE) + (size_t)5 * (NE * 8) + (size_t)tB * 8,
            sA2b, sCCb, HB);
    const float* h1pA = ws + OFF_H1N + sA * CDIM * 3;
    const float* h1pB = ws + OFF_H1N + sB_ * CDIM * 3;
    float GA[6][3], GB[6][3];
#pragma unroll
    for (int of = 0; of < 6; ++of) {
      GA[of][0] = 0.0f; GA[of][1] = 0.0f; GA[of][2] = 0.0f;
      GB[of][0] = 0.0f; GB[of][1] = 0.0f; GB[of][2] = 0.0f;
    }
#pragma unroll 1
    for (int ci = 0; ci < CDIM; ++ci) {
      float bA0 = h1pA[ci * 3 + 0], bA1 = h1pA[ci * 3 + 1], bA2 = h1pA[ci * 3 + 2];
      float bB0 = h1pB[ci * 3 + 0], bB1 = h1pB[ci * 3 + 1], bB2 = h1pB[ci * 3 + 2];
#pragma unroll
      for (int of = 0; of < 6; ++of) {
        float RA = sBB11[ci * 6 + of];
        float RB = RA;
        const float4* wp = (const float4*)(sPB11 + (ci * 6 + of) * 32);
#pragma unroll
        for (int i4 = 0; i4 < 8; ++i4) {
          float4 wv = wp[i4];
          RA = fmaf(HA[4 * i4 + 0], wv.x, RA);
          RB = fmaf(HB[4 * i4 + 0], wv.x, RB);
          RA = fmaf(HA[4 * i4 + 1], wv.y, RA);
          RB = fmaf(HB[4 * i4 + 1], wv.y, RB);
          RA = fmaf(HA[4 * i4 + 2], wv.z, RA);
          RB = fmaf(HB[4 * i4 + 2], wv.z, RB);
          RA = fmaf(HA[4 * i4 + 3], wv.w, RA);
          RB = fmaf(HB[4 * i4 + 3], wv.w, RB);
        }
        GA[of][0] = fmaf(RA, bA0, GA[of][0]);
        GA[of][1] = fmaf(RA, bA1, GA[of][1]);
        GA[of][2] = fmaf(RA, bA2, GA[of][2]);
        GB[of][0] = fmaf(RB, bB0, GB[of][0]);
        GB[of][1] = fmaf(RB, bB1, GB[of][1]);
        GB[of][2] = fmaf(RB, bB2, GB[of][2]);
      }
      SCHED_FENCE();
    }
    {
      float ux = EA.y, uy = EA.z, uz = EA.w;
      float y10 = Y1C * uy, y11 = Y1C * uz, y12 = Y1C * ux;
      float y20 = Y2C1 * ux * uy, y21 = Y2C1 * uy * uz;
      float y22 = Y2C2 * (3.0f * uz * uz - 1.0f);
      float y23 = Y2C1 * ux * uz, y24 = Y2C3 * (ux * ux - uy * uy);
      float S00 = -S6C * y22 - S2C * y24;
      float S11 = 2.0f * S6C * y22;
      float S22 = -S6C * y22 + S2C * y24;
      float S01 = S2C * y21, S02 = S2C * y20, S12 = S2C * y23;
      float4* mp = (float4*)(ws + OFF_MSGB) + tA * 2;
#pragma unroll
      for (int o = 0; o < 2; ++o) {
        float Ao = (o == 0) ? A0A : A1A;
        float m0 = Ao * y10 + K0C * GA[o * 3 + 0][0]
                 + S2C * (y12 * GA[o * 3 + 1][1] - y11 * GA[o * 3 + 1][2])
                 + S00 * GA[o * 3 + 2][0] + S01 * GA[o * 3 + 2][1] + S02 * GA[o * 3 + 2][2];
        float m1 = Ao * y11 + K0C * GA[o * 3 + 0][1]
                 + S2C * (y10 * GA[o * 3 + 1][2] - y12 * GA[o * 3 + 1][0])
                 + S01 * GA[o * 3 + 2][0] + S11 * GA[o * 3 + 2][1] + S12 * GA[o * 3 + 2][2];
        float m2 = Ao * y12 + K0C * GA[o * 3 + 0][2]
                 + S2C * (y11 * GA[o * 3 + 1][0] - y10 * GA[o * 3 + 1][1])
                 + S02 * GA[o * 3 + 2][0] + S12 * GA[o * 3 + 2][1] + S22 * GA[o * 3 + 2][2];
        mp[o] = make_float4(m0, m1, m2, 0.0f);
      }
    }
    {
      float ux = EB.y, uy = EB.z, uz = EB.w;
      float y10 = Y1C * uy, y11 = Y1C * uz, y12 = Y1C * ux;
      float y20 = Y2C1 * ux * uy, y21 = Y2C1 * uy * uz;
      float y22 = Y2C2 * (3.0f * uz * uz - 1.0f);
      float y23 = Y2C1 * ux * uz, y24 = Y2C3 * (ux * ux - uy * uy);
      float S00 = -S6C * y22 - S2C * y24;
      float S11 = 2.0f * S6C * y22;
      float S22 = -S6C * y22 + S2C * y24;
      float S01 = S2C * y21, S02 = S2C * y20, S12 = S2C * y23;
      float4* mp = (float4*)(ws + OFF_MSGB) + tB * 2;
#pragma unroll
      for (int o = 0; o < 2; ++o) {
        float Ao = (o == 0) ? A0B : A1B;
        float m0 = Ao * y10 + K0C * GB[o * 3 + 0][0]
                 + S2C * (y12 * GB[o * 3 + 1][1] - y11 * GB[o * 3 + 1][2])
                 + S00 * GB[o * 3 + 2][0] + S01 * GB[o * 3 + 2][1] + S02 * GB[o * 3 + 2][2];
        float m1 = Ao * y11 + K0C * GB[o * 3 + 0][1]
                 + S2C * (y10 * GB[o * 3 + 1][2] - y12 * GB[o * 3 + 1][0])
                 + S01 * GB[o * 3 + 2][0] + S11 * GB[o * 3 + 2][1] + S12 * GB[o * 3 + 2][2];
        float m2 = Ao * y12 + K0C * GB[o * 3 + 0][2]
                 + S2C * (y11 * GB[o * 3 + 1][0] - y10 * GB[o * 3 + 1][1])
                 + S02 * GB[o * 3 + 2][0] + S12 * GB[o * 3 + 2][1] + S22 * GB[o * 3 + 2][2];
        mp[o] = make_float4(m0, m1, m2, 0.0f);
      }
    }
  }
}

// ---- OLD B (2-edge paired) ----
__global__ __launch_bounds__(256) void k_passB(
    const float* __restrict__ wb01, const float* __restrict__ bb01,
    const float* __restrict__ wb11, const float* __restrict__ bb11,
    float* __restrict__ ws) {
  __shared__ __align__(16) float sW1a[64], sW1b[64], sc1[64], sc2[64];
  __shared__ __align__(16) float sW2T[2048];
  __shared__ __align__(16) float sPB01[1024];
  __shared__ __align__(16) float sPB11[3072];
  __shared__ float sBB01[32];
  __shared__ float sBB11[96];
  int tid = threadIdx.x;
  if (tid < 64) {
    sW1a[tid] = ws[OFF_FW1A + 128 + tid];
    sW1b[tid] = ws[OFF_FW1B + 128 + tid];
    sc1[tid] = ws[OFF_FC1 + 128 + tid];
    sc2[tid] = ws[OFF_FC2 + 128 + tid];
  }
  for (int t = tid; t < 2048; t += 256) sW2T[t] = ws[OFF_FW2T + 4096 + t];
  for (int t = tid; t < 1024; t += 256) {
    int i = t >> 5, c = t & 31;
    int o = c >> 4, ci = c & 15;
    sPB01[(ci * 2 + o) * 32 + i] = wb01[t];
  }
  for (int t = tid; t < 3072; t += 256) {
    int i = t / 96, c = t - i * 96;
    int o = c / 48, rem = c - o * 48;
    int ci = rem / 3, f = rem - ci * 3;
    sPB11[(ci * 6 + o * 3 + f) * 32 + i] = wb11[t];
  }
  if (tid < 32) {
    int o = tid >> 4, ci = tid & 15;
    sBB01[ci * 2 + o] = bb01[tid];
  }
  if (tid < 96) {
    int o = tid / 48, rem = tid - o * 48;
    int ci = rem / 3, f = rem - ci * 3;
    sBB11[ci * 6 + o * 3 + f] = bb11[tid];
  }
  __syncthreads();

  const int* srcs = (const int*)ws + OFF_SRCS;
  const float* wsrt = ws + OFF_WSRT;
  const float4* ecs = (const float4*)(ws + OFF_ECS);
  const int NP = NE / 2;
  int p = blockIdx.x * blockDim.x + tid;
  if (p >= NP) return;
  {
    int tA = 2 * p, tB = 2 * p + 1;
    int sA = srcs[tA], sB_ = srcs[tB];
    float4 EA = ecs[tA], EB = ecs[tB];
    float weA = wsrt[tA], weB = wsrt[tB];

    float HA[MID], HB[MID];
    mlpH2_lds(sW1a, sW1b, sc1, sc2, sW2T, weA, EA.x, weB, EB.x, HA, HB);
    const float* h0pA = ws + OFF_H0N + sA * CDIM;
    const float* h0pB = ws + OFF_H0N + sB_ * CDIM;
    float A0A = 0.0f, A1A = 0.0f, A0B = 0.0f, A1B = 0.0f;
#pragma unroll 1
    for (int ci = 0; ci < CDIM; ++ci) {
      float bA = h0pA[ci], bB = h0pB[ci];
      float R0A = sBB01[ci * 2 + 0], R1A = sBB01[ci * 2 + 1];
      float R0B = R0A, R1B = R1A;
      const float4* p0 = (const float4*)(sPB01 + (ci * 2 + 0) * 32);
      const float4* p1 = (const float4*)(sPB01 + (ci * 2 + 1) * 32);
#pragma unroll
      for (int i4 = 0; i4 < 8; ++i4) {
        float4 w0v = p0[i4], w1v = p1[i4];
        float hA0 = HA[4 * i4 + 0], hB0 = HB[4 * i4 + 0];
        float hA1 = HA[4 * i4 + 1], hB1 = HB[4 * i4 + 1];
        float hA2 = HA[4 * i4 + 2], hB2 = HB[4 * i4 + 2];
        float hA3 = HA[4 * i4 + 3], hB3 = HB[4 * i4 + 3];
        R0A = fmaf(hA0, w0v.x, R0A); R0B = fmaf(hB0, w0v.x, R0B);
        R1A = fmaf(hA0, w1v.x, R1A); R1B = fmaf(hB0, w1v.x, R1B);
        R0A = fmaf(hA1, w0v.y, R0A); R0B = fmaf(hB1, w0v.y, R0B);
        R1A = fmaf(hA1, w1v.y, R1A); R1B = fmaf(hB1, w1v.y, R1B);
        R0A = fmaf(hA2, w0v.z, R0A); R0B = fmaf(hB2, w0v.z, R0B);
        R1A = fmaf(hA2, w1v.z, R1A); R1B = fmaf(hB2, w1v.z, R1B);
        R0A = fmaf(hA3, w0v.w, R0A); R0B = fmaf(hB3, w0v.w, R0B);
        R1A = fmaf(hA3, w1v.w, R1A); R1B = fmaf(hB3, w1v.w, R1B);
      }
      A0A = fmaf(R0A, bA, A0A); A1A = fmaf(R1A, bA, A1A);
      A0B = fmaf(R0B, bB, A0B); A1B = fmaf(R1B, bB, A1B);
      SCHED_FENCE();
    }
    mlpH2_lds(sW1a + 32, sW1b + 32, sc1 + 32, sc2 + 32, sW2T + 1024,
              weA, EA.x, weB, EB.x, HA, HB);
    const float* h1pA = ws + OFF_H1N + sA * CDIM * 3;
    const float* h1pB = ws + OFF_H1N + sB_ * CDIM * 3;
    float GA[6][3], GB[6][3];
#pragma unroll
    for (int of = 0; of < 6; ++of) {
      GA[of][0] = 0.0f; GA[of][1] = 0.0f; GA[of][2] = 0.0f;
      GB[of][0] = 0.0f; GB[of][1] = 0.0f; GB[of][2] = 0.0f;
    }
#pragma unroll 1
    for (int ci = 0; ci < CDIM; ++ci) {
      float bA0 = h1pA[ci * 3 + 0], bA1 = h1pA[ci * 3 + 1], bA2 = h1pA[ci * 3 + 2];
      float bB0 = h1pB[ci * 3 + 0], bB1 = h1pB[ci * 3 + 1], bB2 = h1pB[ci * 3 + 2];
#pragma unroll
      for (int of = 0; of < 6; ++of) {
        float RA = sBB11[ci * 6 + of];
        float RB = RA;
        const float4* wp = (const float4*)(sPB11 + (ci * 6 + of) * 32);
#pragma unroll
        for (int i4 = 0; i4 < 8; ++i4) {
          float4 wv = wp[i4];
          RA = fmaf(HA[4 * i4 + 0], wv.x, RA);
          RB = fmaf(HB[4 * i4 + 0], wv.x, RB);
          RA = fmaf(HA[4 * i4 + 1], wv.y, RA);
          RB = fmaf(HB[4 * i4 + 1], wv.y, RB);
          RA = fmaf(HA[4 * i4 + 2], wv.z, RA);
          RB = fmaf(HB[4 * i4 + 2], wv.z, RB);
          RA = fmaf(HA[4 * i4 + 3], wv.w, RA);
          RB = fmaf(HB[4 * i4 + 3], wv.w, RB);
        }
        GA[of][0] = fmaf(RA, bA0, GA[of][0]);
        GA[of][1] = fmaf(RA, bA1, GA[of][1]);
        GA[of][2] = fmaf(RA, bA2, GA[of][2]);
        GB[of][0] = fmaf(RB, bB0, GB[of][0]);
        GB[of][1] = fmaf(RB, bB1, GB[of][1]);
        GB[of][2] = fmaf(RB, bB2, GB[of][2]);
      }
      SCHED_FENCE();
    }
    {
      float ux = EA.y, uy = EA.z, uz = EA.w;
      float y10 = Y1C * uy, y11 = Y1C * uz, y12 = Y1C * ux;
      float y20 = Y2C1 * ux * uy, y21 = Y2C1 * uy * uz;
      float y22 = Y2C2 * (3.0f * uz * uz - 1.0f);
      float y23 = Y2C1 * ux * uz, y24 = Y2C3 * (ux * ux - uy * uy);
      float S00 = -S6C * y22 - S2C * y24;
      float S11 = 2.0f * S6C * y22;
      float S22 = -S6C * y22 + S2C * y24;
      float S01 = S2C * y21, S02 = S2C * y20, S12 = S2C * y23;
      float4* mp = (float4*)(ws + OFF_MSGB) + tA * 2;
#pragma unroll
      for (int o = 0; o < 2; ++o) {
        float Ao = (o == 0) ? A0A : A1A;
        float m0 = Ao * y10 + K0C * GA[o * 3 + 0][0]
                 + S2C * (y12 * GA[o * 3 + 1][1] - y11 * GA[o * 3 + 1][2])
                 + S00 * GA[o * 3 + 2][0] + S01 * GA[o * 3 + 2][1] + S02 * GA[o * 3 + 2][2];
        float m1 = Ao * y11 + K0C * GA[o * 3 + 0][1]
                 + S2C * (y10 * GA[o * 3 + 1][2] - y12 * GA[o * 3 + 1][0])
                 + S01 * GA[o * 3 + 2][0] + S11 * GA[o * 3 + 2][1] + S12 * GA[o * 3 + 2][2];
        float m2 = Ao * y12 + K0C * GA[o * 3 + 0][2]
                 + S2C * (y11 * GA[o * 3 + 1][0] - y10 * GA[o * 3 + 1][1])
                 + S02 * GA[o * 3 + 2][0] + S12 * GA[o * 3 + 2][1] + S22 * GA[o * 3 + 2][2];
        mp[o] = make_float4(m0, m1, m2, 0.0f);
      }
    }
    {
      float ux = EB.y, uy = EB.z, uz = EB.w;
      float y10 = Y1C * uy, y11 = Y1C * uz, y12 = Y1C * ux;
      float y20 = Y2C1 * ux * uy, y21 = Y2C1 * uy * uz;
      float y22 = Y2C2 * (3.0f * uz * uz - 1.0f);
      float y23 = Y2C1 * ux * uz, y24 = Y2C3 * (ux * ux - uy * uy);
      float S00 = -S6C * y22 - S2C * y24;
      float S11 = 2.0f * S6C * y22;
      float S22 = -S6C * y22 + S2C * y24;
      float S01 = S2C * y21, S02 = S2C * y20, S12 = S2C * y23;
      float4* mp = (float4*)(ws + OFF_MSGB) + tB * 2;
#pragma unroll
      for (int o = 0; o < 2; ++o) {
        float Ao = (o == 0) ? A0B : A1B;
        float m0 = Ao * y10 + K0C * GB[o * 3 + 0][0]
                 + S2C * (y12 * GB[o * 3 + 1][1] - y11 * GB[o * 3 + 1][2])
                 + S00 * GB[o * 3 + 2][0] + S01 * GB[o * 3 + 2][1] + S02 * GB[o * 3 + 2][2];
        float m1 = Ao * y11 + K0C * GB[o * 3 + 0][1]
                 + S2C * (y10 * GB[o * 3 + 1][2] - y12 * GB[o * 3 + 1][0])
                 + S01 * GB[o * 3 + 2][0] + S11 * GB[o * 3 + 2][1] + S12 * GB[o * 3 + 2][2];
        float m2 = Ao * y12 + K0C * GB[o * 3 + 0][2]
                 + S2C * (y11 * GB[o * 3 + 1][0] - y10 * GB[o * 3 + 1][1])
                 + S02 * GB[o * 3 + 2][0] + S12 * GB[o * 3 + 2][1] + S22 * GB[o * 3 + 2][2];
        mp[o] = make_float4(m0, m1, m2, 0.0f);
      }
    }
  }
}

// ---- nodeB ----
__global__ __launch_bounds__(256) void k_nodeB(
    const float* __restrict__ selfB1, float* __restrict__ out,
    const float* __restrict__ ws) {
  int idx = blockIdx.x * blockDim.x + threadIdx.x;
  if (idx >= NN * 6) return;
  int n = idx / 6;
  int q = idx - n * 6;
  int o = q / 3, a = q - o * 3;
  const int* rowptr = (const int*)ws + OFF_ROWPTR;
  int r0 = rowptr[n], r1 = rowptr[n + 1];
  const float* msgB = ws + OFF_MSGB;
  int col = o * 4 + a;
  float sum = 0.0f;
  for (int row = r0; row < r1; ++row) sum += msgB[row * 8 + col];
  float dg = (float)(r1 - r0);
  float iv = 1.0f / fmaxf(dg, 1.0f);
  float mk = dg > 0.0f ? 1.0f : 0.0f;
  const float* h1p = ws + OFF_H1N + n * CDIM * 3;
  float self = 0.0f;
#pragma unroll
  for (int ci = 0; ci < CDIM; ++ci)
    self = fmaf(selfB1[o * CDIM + ci], h1p[ci * 3 + a], self);
  out[idx] = sum * iv + self * mk;
}

extern "C" void kernel_launch(void* const* d_in, const int* in_sizes, int n_in,
                              void* d_out, int out_size, void* d_ws, size_t ws_size,
                              hipStream_t stream) {
  (void)in_sizes; (void)n_in; (void)out_size;
  const int* src = (const int*)d_in[0];
  const int* dst = (const int*)d_in[1];
  const float* pos = (const float*)d_in[2];
  const float* cI = (const float*)d_in[3];
  const float* vI = (const float*)d_in[4];
  const float* w = (const float*)d_in[5];
  const float* rW1 = (const float*)d_in[6];
  const float* rb1 = (const float*)d_in[7];
  const float* rg1 = (const float*)d_in[8];
  const float* rbe1 = (const float*)d_in[9];
  const float* rW2 = (const float*)d_in[10];
  const float* rb2 = (const float*)d_in[11];
  const float* rg2 = (const float*)d_in[12];
  const float* rbe2 = (const float*)d_in[13];
  const float* w3_a00 = (const float*)d_in[14];
  const float* b3_a00 = (const float*)d_in[15];
  const float* w3_a01 = (const float*)d_in[16];
  const float* b3_a01 = (const float*)d_in[17];
  const float* w3_a10 = (const float*)d_in[18];
  const float* b3_a10 = (const float*)d_in[19];
  const float* w3_a11 = (const float*)d_in[20];
  const float* b3_a11 = (const float*)d_in[21];
  const float* w3_b01 = (const float*)d_in[22];
  const float* b3_b01 = (const float*)d_in[23];
  const float* w3_b11 = (const float*)d_in[24];
  const float* b3_b11 = (const float*)d_in[25];
  const float* selfA0 = (const float*)d_in[26];
  const float* selfA1 = (const float*)d_in[27];
  const float* selfB1 = (const float*)d_in[28];
  const float* nbias0 = (const float*)d_in[29];
  const float* nbias1 = (const float*)d_in[30];
  float* ws = (float*)d_ws;
  float* out = (float*)d_out;

  const bool bigws = (ws_size >= WS_WORDS_NEEDED * 4ULL);

  hipMemsetAsync(d_ws, 0, (size_t)ZERO_WORDS * 4, stream);

  k_hist<<<1250, 256, 0, stream>>>(dst, ws);
  k_scan<<<1, 256, 0, stream>>>(ws);
  k_scatter<<<1250, 256, 0, stream>>>(dst, ws);
  k_geo<<<1250, 256, 0, stream>>>(src, dst, pos, w, ws);
  k_fin1<<<1, 192, 0, stream>>>(rW1, rb1, rg1, rbe1, ws);

  if (bigws) {
    k_mlp<<<1250, 256, 0, stream>>>(rW2, rb2, ws);
    k_stats2P<<<dim3(256, 6), 256, 0, stream>>>(ws);
    k_fin2<<<1, 192, 0, stream>>>(rb2, rg2, rbe2, ws);
    k_passA0P<<<1250, 256, 0, stream>>>(cI, vI, w3_a00, b3_a00, w3_a10, b3_a10, ws);
    k_passA1P<<<1250, 256, 0, stream>>>(cI, vI, w3_a01, b3_a01, w3_a11, b3_a11, ws);
    k_nodeA<<<1250, 256, 0, stream>>>(cI, vI, selfA0, selfA1, nbias0, nbias1, ws);
    k_passBP<<<625, 256, 0, stream>>>(w3_b01, b3_b01, w3_b11, b3_b11, ws);
  } else {
    k_stats2<<<dim3(256, 6, 2), 256, 0, stream>>>(rW2, rb2, ws);
    k_fin2<<<1, 192, 0, stream>>>(rb2, rg2, rbe2, ws);
    k_fold2<<<24, 256, 0, stream>>>(rW2, ws);
    k_passA0<<<1250, 256, 0, stream>>>(cI, vI, w3_a00, b3_a00, w3_a10, b3_a10, ws);
    k_passA1<<<1250, 256, 0, stream>>>(cI, vI, w3_a01, b3_a01, w3_a11, b3_a11, ws);
    k_nodeA<<<1250, 256, 0, stream>>>(cI, vI, selfA0, selfA1, nbias0, nbias1, ws);
    k_passB<<<625, 256, 0, stream>>>(w3_b01, b3_b01, w3_b11, b3_b11, ws);
  }
  k_nodeB<<<469, 256, 0, stream>>>(selfB1, out, ws);
}

// Round 36
// 467.574 us; speedup vs baseline: 1.1572x; 1.1572x over previous
//
#include <hip/hip_runtime.h>

#define NN 20000
#define NE 320000
#define CDIM 16
#define MID 32
#define EPSF 1e-8f
#define NBLK 79   // ceil(NN/256)

#define SCHED_FENCE() __builtin_amdgcn_sched_barrier(0)

// ---- workspace word (4B) offsets ----
#define OFF_DEGI   848         // 20000 int
#define ZERO_WORDS 20848
#define OFF_ROWPTR 20848       // 20001 int
#define OFF_CURSOR 40864       // 20000 int
#define OFF_EORDER 60864       // 320000 int (also scratch: scan aux before scatter)
#define OFF_SRCS   380864      // 320000 int  (src in sorted order)
#define OFF_WSRT   700864      // 320000 f    (w in sorted order)
#define OFF_FW1A   1020864     // 192
#define OFF_FW1B   1021056     // 192
#define OFF_FC1    1021248     // 192
#define OFF_BN2A   1021440     // 192
#define OFF_FC2    1021632     // 192
#define OFF_FW2T   1021824     // 6144
#define OFF_ECS    1027968     // 1280000 (float4, SORTED order)
#define OFF_H0N    2307968     // 320000
#define OFF_H1N    2627968     // 960000
#define OFF_MSGA0  3587968     // 5120000
#define OFF_MSGA1  8707968     // 15360000 (GROUP-MAJOR: 4 planes of NE*12)
#define OFF_MSGB   24067968    // 2560000 (8 f/edge, padded)

#define Y0C   0.28209479177387814f
#define Y1C   0.4886025119029199f
#define Y2C1  1.0925484305920792f
#define Y2C2  0.31539156525252005f
#define Y2C3  0.5462742152960396f
#define S2C   0.7071067811865476f
#define S6C   0.4082482904638631f
#define K0C   0.16286750396763996f

__device__ __forceinline__ void atomAddD(double* p, double v) {
  unsafeAtomicAdd(p, v);
}

// Single-edge MLP, LDS weights, float4 (ds_read_b128) reads.
__device__ __forceinline__ void mlpH_lds(
    const float* __restrict__ a1, const float* __restrict__ b1v,
    const float* __restrict__ c1, const float* __restrict__ c2,
    const float* __restrict__ W2T, float we, float r, float* H) {
  float h[MID];
#pragma unroll
  for (int j4 = 0; j4 < 8; ++j4) {
    float4 av = ((const float4*)a1)[j4];
    float4 bv = ((const float4*)b1v)[j4];
    float4 cv = ((const float4*)c1)[j4];
    h[4 * j4 + 0] = fmaxf(fmaf(we, av.x, fmaf(r, bv.x, cv.x)), 0.0f);
    h[4 * j4 + 1] = fmaxf(fmaf(we, av.y, fmaf(r, bv.y, cv.y)), 0.0f);
    h[4 * j4 + 2] = fmaxf(fmaf(we, av.z, fmaf(r, bv.z, cv.z)), 0.0f);
    h[4 * j4 + 3] = fmaxf(fmaf(we, av.w, fmaf(r, bv.w, cv.w)), 0.0f);
  }
  SCHED_FENCE();
#pragma unroll
  for (int jg = 0; jg < 8; ++jg) {
#pragma unroll
    for (int jq = 0; jq < 4; ++jq) {
      const int j = jg * 4 + jq;
      float acc = c2[j];
      const float4* wp = (const float4*)(W2T + j * MID);
#pragma unroll
      for (int i4 = 0; i4 < 8; ++i4) {
        float4 wv = wp[i4];
        acc = fmaf(h[4 * i4 + 0], wv.x, acc);
        acc = fmaf(h[4 * i4 + 1], wv.y, acc);
        acc = fmaf(h[4 * i4 + 2], wv.z, acc);
        acc = fmaf(h[4 * i4 + 3], wv.w, acc);
      }
      H[j] = fmaxf(acc, 0.0f);
    }
    SCHED_FENCE();
  }
}

// Two-edge MLP, LDS weights, float4 reads — passB only (best measured there).
__device__ __forceinline__ void mlpH2_lds(
    const float* __restrict__ a1, const float* __restrict__ b1v,
    const float* __restrict__ c1, const float* __restrict__ c2,
    const float* __restrict__ W2T,
    float weA, float rA, float weB, float rB,
    float* HA, float* HB) {
  float hA[MID], hB[MID];
#pragma unroll
  for (int j4 = 0; j4 < 8; ++j4) {
    float4 av = ((const float4*)a1)[j4];
    float4 bv = ((const float4*)b1v)[j4];
    float4 cv = ((const float4*)c1)[j4];
    hA[4 * j4 + 0] = fmaxf(fmaf(weA, av.x, fmaf(rA, bv.x, cv.x)), 0.0f);
    hB[4 * j4 + 0] = fmaxf(fmaf(weB, av.x, fmaf(rB, bv.x, cv.x)), 0.0f);
    hA[4 * j4 + 1] = fmaxf(fmaf(weA, av.y, fmaf(rA, bv.y, cv.y)), 0.0f);
    hB[4 * j4 + 1] = fmaxf(fmaf(weB, av.y, fmaf(rB, bv.y, cv.y)), 0.0f);
    hA[4 * j4 + 2] = fmaxf(fmaf(weA, av.z, fmaf(rA, bv.z, cv.z)), 0.0f);
    hB[4 * j4 + 2] = fmaxf(fmaf(weB, av.z, fmaf(rB, bv.z, cv.z)), 0.0f);
    hA[4 * j4 + 3] = fmaxf(fmaf(weA, av.w, fmaf(rA, bv.w, cv.w)), 0.0f);
    hB[4 * j4 + 3] = fmaxf(fmaf(weB, av.w, fmaf(rB, bv.w, cv.w)), 0.0f);
  }
  SCHED_FENCE();
#pragma unroll
  for (int jg = 0; jg < 8; ++jg) {
#pragma unroll
    for (int jq = 0; jq < 4; ++jq) {
      const int j = jg * 4 + jq;
      float c2v = c2[j];
      float accA = c2v, accB = c2v;
      const float4* wp = (const float4*)(W2T + j * MID);
#pragma unroll
      for (int i4 = 0; i4 < 8; ++i4) {
        float4 wv = wp[i4];
        accA = fmaf(hA[4 * i4 + 0], wv.x, accA);
        accB = fmaf(hB[4 * i4 + 0], wv.x, accB);
        accA = fmaf(hA[4 * i4 + 1], wv.y, accA);
        accB = fmaf(hB[4 * i4 + 1], wv.y, accB);
        accA = fmaf(hA[4 * i4 + 2], wv.z, accA);
        accB = fmaf(hB[4 * i4 + 2], wv.z, accB);
        accA = fmaf(hA[4 * i4 + 3], wv.w, accA);
        accB = fmaf(hB[4 * i4 + 3], wv.w, accB);
      }
      HA[j] = fmaxf(accA, 0.0f);
      HB[j] = fmaxf(accB, 0.0f);
    }
    SCHED_FENCE();
  }
}

// ---- degree histogram ----
__global__ __launch_bounds__(256) void k_hist(
    const int* __restrict__ dst, float* __restrict__ ws) {
  int e = blockIdx.x * blockDim.x + threadIdx.x;
  if (e >= NE) return;
  atomicAdd((int*)ws + OFF_DEGI + dst[e], 1);
}

// ---- multi-block scan: phase 1 (per-block exclusive scan + block totals) ----
__global__ __launch_bounds__(256) void k_scan1(float* __restrict__ ws) {
  __shared__ int buf[256];
  const int* degi = (const int*)ws + OFF_DEGI;
  int* rowptr = (int*)ws + OFF_ROWPTR;
  int* aux = (int*)ws + OFF_EORDER;   // scratch; scatter overwrites later
  int tid = threadIdx.x;
  int i = blockIdx.x * 256 + tid;
  int v = (i < NN) ? degi[i] : 0;
  buf[tid] = v;
  __syncthreads();
  for (int off = 1; off < 256; off <<= 1) {
    int t = buf[tid];
    int add = (tid >= off) ? buf[tid - off] : 0;
    __syncthreads();
    buf[tid] = t + add;
    __syncthreads();
  }
  if (i < NN) rowptr[i] = buf[tid] - v;   // exclusive within block
  if (tid == 255) aux[blockIdx.x] = buf[255];
}

// ---- phase 2: scan the NBLK block totals (single small block) ----
__global__ void k_scan2(float* __restrict__ ws) {
  __shared__ int s[128];
  int* aux = (int*)ws + OFF_EORDER;
  int tid = threadIdx.x;
  int v = (tid < NBLK) ? aux[tid] : 0;
  s[tid] = v;
  __syncthreads();
  for (int off = 1; off < 128; off <<= 1) {
    int t = s[tid];
    int add = (tid >= off) ? s[tid - off] : 0;
    __syncthreads();
    s[tid] = t + add;
    __syncthreads();
  }
  if (tid < NBLK) aux[tid] = s[tid] - v;  // exclusive block offsets
}

// ---- phase 3: add block offsets, init cursor, set rowptr[NN] ----
__global__ __launch_bounds__(256) void k_scan3(float* __restrict__ ws) {
  int* rowptr = (int*)ws + OFF_ROWPTR;
  int* cursor = (int*)ws + OFF_CURSOR;
  const int* aux = (const int*)ws + OFF_EORDER;
  int tid = threadIdx.x;
  int i = blockIdx.x * 256 + tid;
  if (i < NN) {
    int r = rowptr[i] + aux[blockIdx.x];
    rowptr[i] = r;
    cursor[i] = r;
  }
  if (i == 0) rowptr[NN] = NE;  // total degree == edge count, statically known
}

__global__ __launch_bounds__(256) void k_scatter(
    const int* __restrict__ dst, float* __restrict__ ws) {
  int e = blockIdx.x * blockDim.x + threadIdx.x;
  if (e >= NE) return;
  int* cursor = (int*)ws + OFF_CURSOR;
  int* eorder = (int*)ws + OFF_EORDER;
  int d = dst[e];
  int p = atomicAdd(cursor + d, 1);
  eorder[p] = e;
}

// ---- geo: gather edge data into SORTED order + f64 stats1 ----
__global__ __launch_bounds__(256) void k_geo(
    const int* __restrict__ src, const int* __restrict__ dst,
    const float* __restrict__ pos, const float* __restrict__ w,
    float* __restrict__ ws) {
  __shared__ double sred[20];
  double lw = 0, lr = 0, lww = 0, lrr = 0, lwr = 0;
  const int* eorder = (const int*)ws + OFF_EORDER;
  int* srcs = (int*)ws + OFF_SRCS;
  float* wsrt = ws + OFF_WSRT;
  float4* ecs = (float4*)(ws + OFF_ECS);
  for (int t = blockIdx.x * blockDim.x + threadIdx.x; t < NE;
       t += gridDim.x * blockDim.x) {
    int e = eorder[t];
    int s = src[e], d = dst[e];
    float dx = pos[3 * d + 0] - pos[3 * s + 0];
    float dy = pos[3 * d + 1] - pos[3 * s + 1];
    float dz = pos[3 * d + 2] - pos[3 * s + 2];
    float r = sqrtf(dx * dx + dy * dy + dz * dz);
    float ri = 1.0f / fmaxf(r, EPSF);
    ecs[t] = make_float4(r, dx * ri, dy * ri, dz * ri);
    float we = w[e];
    wsrt[t] = we;
    srcs[t] = s;
    double wd = (double)we, rd = (double)r;
    lw += wd; lr += rd; lww += wd * wd; lrr += rd * rd; lwr += wd * rd;
  }
#pragma unroll
  for (int d = 32; d >= 1; d >>= 1) {
    lw += __shfl_xor(lw, d);
    lr += __shfl_xor(lr, d);
    lww += __shfl_xor(lww, d);
    lrr += __shfl_xor(lrr, d);
    lwr += __shfl_xor(lwr, d);
  }
  int wid = threadIdx.x >> 6;
  if ((threadIdx.x & 63) == 0) {
    sred[0 * 4 + wid] = lw;
    sred[1 * 4 + wid] = lr;
    sred[2 * 4 + wid] = lww;
    sred[3 * 4 + wid] = lrr;
    sred[4 * 4 + wid] = lwr;
  }
  __syncthreads();
  if (threadIdx.x < 5) {
    double v = sred[threadIdx.x * 4 + 0] + sred[threadIdx.x * 4 + 1]
             + sred[threadIdx.x * 4 + 2] + sred[threadIdx.x * 4 + 3];
    atomAddD((double*)ws + threadIdx.x * 8, v);
  }
}

// ---- fin1 ----
__global__ void k_fin1(const float* __restrict__ rW1, const float* __restrict__ rb1,
                       const float* __restrict__ rg1, const float* __restrict__ rbe1,
                       float* __restrict__ ws) {
  int t = threadIdx.x;
  int k = t >> 5, j = t & 31;
  const double* s1 = (const double*)ws;
  double Sw = s1[0], Sr = s1[8], Sww = s1[16], Srr = s1[24], Swr = s1[32];
  const double inv = 1.0 / (double)NE;
  double W0 = (double)rW1[k * 64 + j], W1 = (double)rW1[k * 64 + 32 + j];
  double b = (double)rb1[k * 32 + j];
  double mlin = (Sw * W0 + Sr * W1) * inv;
  double mu = mlin + b;
  double ex2 = (Sww * W0 * W0 + Srr * W1 * W1 + 2.0 * Swr * W0 * W1) * inv
             + 2.0 * b * mlin + b * b;
  double var = ex2 - mu * mu;
  double a = (double)rg1[k * 32 + j] / sqrt(var + 1e-5);
  ws[OFF_FW1A + t] = (float)(W0 * a);
  ws[OFF_FW1B + t] = (float)(W1 * a);
  ws[OFF_FC1 + t] = (float)((double)rbe1[k * 32 + j] - mlin * a);
}

// ---- stats2: 2 edges/thread, z=2, float4 LDS weight reads ----
__global__ __launch_bounds__(256) void k_stats2(
    const float* __restrict__ rW2, const float* __restrict__ rb2,
    float* __restrict__ ws) {
  const int k = blockIdx.y;
  const int j0 = blockIdx.z * 16;
  __shared__ __align__(16) float sW1a[32], sW1b[32], sc1[32];
  __shared__ __align__(16) float sW2c[512];
  __shared__ float sb2[16];
  __shared__ float sredf[2][16][4];
  int tid = threadIdx.x;
  if (tid < 32) {
    sW1a[tid] = ws[OFF_FW1A + k * 32 + tid];
    sW1b[tid] = ws[OFF_FW1B + k * 32 + tid];
    sc1[tid] = ws[OFF_FC1 + k * 32 + tid];
  }
  if (tid < 16) sb2[tid] = rb2[k * 32 + j0 + tid];
  for (int t = tid; t < 512; t += 256) {
    int jj = t >> 5, i = t & 31;
    sW2c[t] = rW2[k * 1024 + i * 32 + j0 + jj];
  }
  __syncthreads();
  const float4* ecs = (const float4*)(ws + OFF_ECS);
  const float* wsrt = ws + OFF_WSRT;
  float lsum[16], lsq[16];
#pragma unroll
  for (int jj = 0; jj < 16; ++jj) { lsum[jj] = 0.0f; lsq[jj] = 0.0f; }
  const int NP = NE / 2;
  for (int p = blockIdx.x * blockDim.x + tid; p < NP;
       p += gridDim.x * blockDim.x) {
    int e0 = 2 * p;
    float r0 = ecs[e0].x, r1 = ecs[e0 + 1].x;
    float w0 = wsrt[e0], w1 = wsrt[e0 + 1];
    float h0[MID], h1[MID];
#pragma unroll
    for (int j4 = 0; j4 < 8; ++j4) {
      float4 av = ((const float4*)sW1a)[j4];
      float4 bv = ((const float4*)sW1b)[j4];
      float4 cv = ((const float4*)sc1)[j4];
      h0[4 * j4 + 0] = fmaxf(fmaf(w0, av.x, fmaf(r0, bv.x, cv.x)), 0.0f);
      h1[4 * j4 + 0] = fmaxf(fmaf(w1, av.x, fmaf(r1, bv.x, cv.x)), 0.0f);
      h0[4 * j4 + 1] = fmaxf(fmaf(w0, av.y, fmaf(r0, bv.y, cv.y)), 0.0f);
      h1[4 * j4 + 1] = fmaxf(fmaf(w1, av.y, fmaf(r1, bv.y, cv.y)), 0.0f);
      h0[4 * j4 + 2] = fmaxf(fmaf(w0, av.z, fmaf(r0, bv.z, cv.z)), 0.0f);
      h1[4 * j4 + 2] = fmaxf(fmaf(w1, av.z, fmaf(r1, bv.z, cv.z)), 0.0f);
      h0[4 * j4 + 3] = fmaxf(fmaf(w0, av.w, fmaf(r0, bv.w, cv.w)), 0.0f);
      h1[4 * j4 + 3] = fmaxf(fmaf(w1, av.w, fmaf(r1, bv.w, cv.w)), 0.0f);
    }
    SCHED_FENCE();
#pragma unroll
    for (int jg = 0; jg < 4; ++jg) {
#pragma unroll
      for (int jq = 0; jq < 4; ++jq) {
        const int jj = jg * 4 + jq;
        float aE0 = sb2[jj], aE1 = sb2[jj];
        const float4* wp = (const float4*)(sW2c + jj * 32);
#pragma unroll
        for (int i4 = 0; i4 < 8; ++i4) {
          float4 wv = wp[i4];
          aE0 = fmaf(h0[4 * i4 + 0], wv.x, aE0);
          aE1 = fmaf(h1[4 * i4 + 0], wv.x, aE1);
          aE0 = fmaf(h0[4 * i4 + 1], wv.y, aE0);
          aE1 = fmaf(h1[4 * i4 + 1], wv.y, aE1);
          aE0 = fmaf(h0[4 * i4 + 2], wv.z, aE0);
          aE1 = fmaf(h1[4 * i4 + 2], wv.z, aE1);
          aE0 = fmaf(h0[4 * i4 + 3], wv.w, aE0);
          aE1 = fmaf(h1[4 * i4 + 3], wv.w, aE1);
        }
        lsum[jj] += aE0 + aE1;
        lsq[jj] = fmaf(aE0, aE0, fmaf(aE1, aE1, lsq[jj]));
      }
      SCHED_FENCE();
    }
  }
  int wid = tid >> 6;
#pragma unroll
  for (int jj = 0; jj < 16; ++jj) {
    float v1 = lsum[jj], v2 = lsq[jj];
#pragma unroll
    for (int d = 32; d >= 1; d >>= 1) {
      v1 += __shfl_xor(v1, d);
      v2 += __shfl_xor(v2, d);
    }
    if ((tid & 63) == 0) {
      sredf[0][jj][wid] = v1;
      sredf[1][jj][wid] = v2;
    }
  }
  __syncthreads();
  if (tid < 32) {
    int jj = tid & 15, which = tid >> 4;
    float v = sredf[which][jj][0] + sredf[which][jj][1]
            + sredf[which][jj][2] + sredf[which][jj][3];
    double* s2 = (double*)(ws + 80);
    atomAddD(s2 + k * 64 + which * 32 + j0 + jj, (double)v);
  }
}

__global__ void k_fin2(const float* __restrict__ rb2,
                       const float* __restrict__ rg2, const float* __restrict__ rbe2,
                       float* __restrict__ ws) {
  int t = threadIdx.x;
  int k = t >> 5, j = t & 31;
  const double* s2 = (const double*)(ws + 80);
  const double inv = 1.0 / (double)NE;
  double mu = s2[k * 64 + j] * inv;
  double ex2 = s2[k * 64 + 32 + j] * inv;
  double var = ex2 - mu * mu;
  double a = (double)rg2[t] / sqrt(var + 1e-5);
  ws[OFF_BN2A + t] = (float)a;
  ws[OFF_FC2 + t] = (float)((double)rbe2[t] + ((double)rb2[t] - mu) * a);
}

__global__ __launch_bounds__(256) void k_fold2(const float* __restrict__ rW2,
                                               float* __restrict__ ws) {
  int idx = blockIdx.x * blockDim.x + threadIdx.x;
  if (idx >= 6144) return;
  int k = idx >> 10, rem = idx & 1023;
  int j = rem >> 5, i = rem & 31;
  ws[OFF_FW2T + idx] = rW2[k * 1024 + i * 32 + j] * ws[OFF_BN2A + k * 32 + j];
}

// ---- A0 (1-edge, grid 1250 = 4.9 waves/SIMD): nets 0,2 -> m0 -> msgA0 ----
__global__ __launch_bounds__(256) void k_passA0(
    const float* __restrict__ cI, const float* __restrict__ vI,
    const float* __restrict__ w00, const float* __restrict__ b00,
    const float* __restrict__ w10, const float* __restrict__ b10,
    float* __restrict__ ws) {
  __shared__ __align__(16) float sW1a[64], sW1b[64], sc1[64], sc2[64];
  __shared__ __align__(16) float sW2T[2048];
  __shared__ __align__(16) float sP00[512], sP10[512];
  __shared__ float sB00[16], sB10[16];
  int tid = threadIdx.x;
  if (tid < 32) {
    sW1a[tid] = ws[OFF_FW1A + tid];       sW1a[32 + tid] = ws[OFF_FW1A + 64 + tid];
    sW1b[tid] = ws[OFF_FW1B + tid];       sW1b[32 + tid] = ws[OFF_FW1B + 64 + tid];
    sc1[tid]  = ws[OFF_FC1 + tid];        sc1[32 + tid]  = ws[OFF_FC1 + 64 + tid];
    sc2[tid]  = ws[OFF_FC2 + tid];        sc2[32 + tid]  = ws[OFF_FC2 + 64 + tid];
  }
  for (int t = tid; t < 2048; t += 256) {
    sW2T[t] = ws[OFF_FW2T + ((t < 1024) ? t : (1024 + t))];
  }
  for (int t = tid; t < 512; t += 256) {
    int i = t >> 4, co = t & 15;
    sP00[co * 32 + i] = w00[t];
    sP10[co * 32 + i] = w10[t];
  }
  if (tid < 16) { sB00[tid] = b00[tid]; sB10[tid] = b10[tid]; }
  __syncthreads();

  const int* srcs = (const int*)ws + OFF_SRCS;
  const float* wsrt = ws + OFF_WSRT;
  const float4* ecs = (const float4*)(ws + OFF_ECS);
  int t = blockIdx.x * blockDim.x + tid;
  if (t >= NE) return;
  int s = srcs[t];
  float4 E = ecs[t];
  float we = wsrt[t];
  float cs = cI[s];
  float v0 = vI[3 * s + 0], v1 = vI[3 * s + 1], v2 = vI[3 * s + 2];
  float dY1v = Y1C * (E.z * v0 + E.w * v1 + E.y * v2);

  float H[MID], m0[CDIM];
  mlpH_lds(sW1a, sW1b, sc1, sc2, sW2T, we, E.x, H);
  float f0 = Y0C * cs;
#pragma unroll
  for (int cg = 0; cg < 4; ++cg) {
#pragma unroll
    for (int cq = 0; cq < 4; ++cq) {
      const int co = cg * 4 + cq;
      float a = sB00[co];
      const float4* wp = (const float4*)(sP00 + co * 32);
#pragma unroll
      for (int i4 = 0; i4 < 8; ++i4) {
        float4 wv = wp[i4];
        a = fmaf(H[4 * i4 + 0], wv.x, a);
        a = fmaf(H[4 * i4 + 1], wv.y, a);
        a = fmaf(H[4 * i4 + 2], wv.z, a);
        a = fmaf(H[4 * i4 + 3], wv.w, a);
      }
      m0[co] = a * f0;
    }
    SCHED_FENCE();
  }
  mlpH_lds(sW1a + 32, sW1b + 32, sc1 + 32, sc2 + 32, sW2T + 1024, we, E.x, H);
#pragma unroll
  for (int cg = 0; cg < 4; ++cg) {
#pragma unroll
    for (int cq = 0; cq < 4; ++cq) {
      const int co = cg * 4 + cq;
      float a = sB10[co];
      const float4* wp = (const float4*)(sP10 + co * 32);
#pragma unroll
      for (int i4 = 0; i4 < 8; ++i4) {
        float4 wv = wp[i4];
        a = fmaf(H[4 * i4 + 0], wv.x, a);
        a = fmaf(H[4 * i4 + 1], wv.y, a);
        a = fmaf(H[4 * i4 + 2], wv.z, a);
        a = fmaf(H[4 * i4 + 3], wv.w, a);
      }
      m0[co] = fmaf(a, dY1v, m0[co]);
    }
    SCHED_FENCE();
  }
  float4* mp = (float4*)(ws + OFF_MSGA0) + t * 4;
#pragma unroll
  for (int q = 0; q < 4; ++q)
    mp[q] = make_float4(m0[4 * q], m0[4 * q + 1], m0[4 * q + 2], m0[4 * q + 3]);
}

// ---- A1 (1-edge, grid 1250): nets 1,3 -> m1 -> msgA1 (GROUP-MAJOR planes) ----
__global__ __launch_bounds__(256) void k_passA1(
    const float* __restrict__ cI, const float* __restrict__ vI,
    const float* __restrict__ w01, const float* __restrict__ b01,
    const float* __restrict__ w11, const float* __restrict__ b11,
    float* __restrict__ ws) {
  __shared__ __align__(16) float sW1a[64], sW1b[64], sc1[64], sc2[64];
  __shared__ __align__(16) float sW2T[2048];
  __shared__ __align__(16) float sP01[512], sP11[1536];
  __shared__ float sB01[16], sB11[48];
  int tid = threadIdx.x;
  if (tid < 32) {
    sW1a[tid] = ws[OFF_FW1A + 32 + tid];  sW1a[32 + tid] = ws[OFF_FW1A + 96 + tid];
    sW1b[tid] = ws[OFF_FW1B + 32 + tid];  sW1b[32 + tid] = ws[OFF_FW1B + 96 + tid];
    sc1[tid]  = ws[OFF_FC1 + 32 + tid];   sc1[32 + tid]  = ws[OFF_FC1 + 96 + tid];
    sc2[tid]  = ws[OFF_FC2 + 32 + tid];   sc2[32 + tid]  = ws[OFF_FC2 + 96 + tid];
  }
  for (int t = tid; t < 1024; t += 256) {
    sW2T[t] = ws[OFF_FW2T + 1024 + t];
    sW2T[1024 + t] = ws[OFF_FW2T + 3072 + t];
  }
  for (int t = tid; t < 512; t += 256) {
    int i = t >> 4, co = t & 15;
    sP01[co * 32 + i] = w01[t];
  }
  for (int t = tid; t < 1536; t += 256) {
    int i = t / 48, c = t - i * 48;
    sP11[c * 32 + i] = w11[t];
  }
  if (tid < 16) sB01[tid] = b01[tid];
  if (tid < 48) sB11[tid] = b11[tid];
  __syncthreads();

  const int* srcs = (const int*)ws + OFF_SRCS;
  const float* wsrt = ws + OFF_WSRT;
  const float4* ecs = (const float4*)(ws + OFF_ECS);
  int t = blockIdx.x * blockDim.x + tid;
  if (t >= NE) return;
  int s = srcs[t];
  float4 E = ecs[t];
  float we = wsrt[t];
  float cs = cI[s];

  float H[MID];
  float ra[16];
  mlpH_lds(sW1a, sW1b, sc1, sc2, sW2T, we, E.x, H);
#pragma unroll
  for (int cg = 0; cg < 4; ++cg) {
#pragma unroll
    for (int cq = 0; cq < 4; ++cq) {
      const int co = cg * 4 + cq;
      float a = sB01[co];
      const float4* wp = (const float4*)(sP01 + co * 32);
#pragma unroll
      for (int i4 = 0; i4 < 8; ++i4) {
        float4 wv = wp[i4];
        a = fmaf(H[4 * i4 + 0], wv.x, a);
        a = fmaf(H[4 * i4 + 1], wv.y, a);
        a = fmaf(H[4 * i4 + 2], wv.z, a);
        a = fmaf(H[4 * i4 + 3], wv.w, a);
      }
      ra[co] = a;
    }
    SCHED_FENCE();
  }
  mlpH_lds(sW1a + 32, sW1b + 32, sc1 + 32, sc2 + 32, sW2T + 1024, we, E.x, H);
  float y10 = Y1C * E.z, y11 = Y1C * E.w, y12 = Y1C * E.y;
  float KV[3][3];
  {
    float ux = E.y, uy = E.z, uz = E.w;
    float y20 = Y2C1 * ux * uy, y21 = Y2C1 * uy * uz;
    float y22 = Y2C2 * (3.0f * uz * uz - 1.0f);
    float y23 = Y2C1 * ux * uz, y24 = Y2C3 * (ux * ux - uy * uy);
    float S00 = -S6C * y22 - S2C * y24;
    float S11 = 2.0f * S6C * y22;
    float S22 = -S6C * y22 + S2C * y24;
    float S01 = S2C * y21, S02 = S2C * y20, S12 = S2C * y23;
    float v0 = vI[3 * s + 0], v1 = vI[3 * s + 1], v2 = vI[3 * s + 2];
    KV[0][0] = K0C * v0; KV[0][1] = K0C * v1; KV[0][2] = K0C * v2;
    KV[1][0] = S2C * (y12 * v1 - y11 * v2);
    KV[1][1] = S2C * (y10 * v2 - y12 * v0);
    KV[1][2] = S2C * (y11 * v0 - y10 * v1);
    KV[2][0] = S00 * v0 + S01 * v1 + S02 * v2;
    KV[2][1] = S01 * v0 + S11 * v1 + S12 * v2;
    KV[2][2] = S02 * v0 + S12 * v1 + S22 * v2;
  }
  float cy0 = cs * y10, cy1 = cs * y11, cy2 = cs * y12;
#pragma unroll 1
  for (int g = 0; g < 4; ++g) {
    float a[12];
#pragma unroll
    for (int q = 0; q < 4; ++q) {
      int co = g * 4 + q;
      float R0 = sB11[co * 3 + 0], R1 = sB11[co * 3 + 1], R2 = sB11[co * 3 + 2];
      const float4* p0 = (const float4*)(sP11 + (co * 3 + 0) * 32);
      const float4* p1 = (const float4*)(sP11 + (co * 3 + 1) * 32);
      const float4* p2 = (const float4*)(sP11 + (co * 3 + 2) * 32);
#pragma unroll
      for (int i4 = 0; i4 < 8; ++i4) {
        float4 w0v = p0[i4], w1v = p1[i4], w2v = p2[i4];
        float h0 = H[4 * i4 + 0], h1 = H[4 * i4 + 1];
        float h2 = H[4 * i4 + 2], h3 = H[4 * i4 + 3];
        R0 = fmaf(h0, w0v.x, R0); R1 = fmaf(h0, w1v.x, R1); R2 = fmaf(h0, w2v.x, R2);
        R0 = fmaf(h1, w0v.y, R0); R1 = fmaf(h1, w1v.y, R1); R2 = fmaf(h1, w2v.y, R2);
        R0 = fmaf(h2, w0v.z, R0); R1 = fmaf(h2, w1v.z, R1); R2 = fmaf(h2, w2v.z, R2);
        R0 = fmaf(h3, w0v.w, R0); R1 = fmaf(h3, w1v.w, R1); R2 = fmaf(h3, w2v.w, R2);
      }
      float r_ = ra[co];
      a[q * 3 + 0] = fmaf(r_, cy0, R0 * KV[0][0] + R1 * KV[1][0] + R2 * KV[2][0]);
      a[q * 3 + 1] = fmaf(r_, cy1, R0 * KV[0][1] + R1 * KV[1][1] + R2 * KV[2][1]);
      a[q * 3 + 2] = fmaf(r_, cy2, R0 * KV[0][2] + R1 * KV[1][2] + R2 * KV[2][2]);
    }
    float4* mp = (float4*)(ws + OFF_MSGA1 + g * (NE * 12)) + t * 3;
    mp[0] = make_float4(a[0], a[1], a[2], a[3]);
    mp[1] = make_float4(a[4], a[5], a[6], a[7]);
    mp[2] = make_float4(a[8], a[9], a[10], a[11]);
    SCHED_FENCE();
  }
}

// ---- nodeA (msgA1 is group-major: g = co>>2, q = co&3) ----
__global__ __launch_bounds__(256) void k_nodeA(
    const float* __restrict__ cI, const float* __restrict__ vI,
    const float* __restrict__ selfA0, const float* __restrict__ selfA1,
    const float* __restrict__ nbias0, const float* __restrict__ nbias1,
    float* __restrict__ ws) {
  int idx = blockIdx.x * blockDim.x + threadIdx.x;
  if (idx >= NN * CDIM) return;
  int n = idx >> 4, co = idx & 15;
  const int* rowptr = (const int*)ws + OFF_ROWPTR;
  int r0 = rowptr[n], r1 = rowptr[n + 1];
  const float* mA0 = ws + OFF_MSGA0;
  const float* mA1 = ws + OFF_MSGA1 + (co >> 2) * (NE * 12) + (co & 3) * 3;
  float x0 = 0.0f, xa = 0.0f, xb = 0.0f, xc = 0.0f;
  for (int row = r0; row < r1; ++row) {
    x0 += mA0[row * 16 + co];
    xa += mA1[row * 12 + 0];
    xb += mA1[row * 12 + 1];
    xc += mA1[row * 12 + 2];
  }
  float dg = (float)(r1 - r0);
  float iv = 1.0f / fmaxf(dg, 1.0f);
  float mk = dg > 0.0f ? 1.0f : 0.0f;
  x0 = x0 * iv + selfA0[co] * cI[n] * mk;
  float n0 = sqrtf(x0 * x0 + 1e-12f);
  ws[OFF_H0N + idx] = fmaxf(n0 + nbias0[co], 0.0f) * (x0 / fmaxf(n0, EPSF));
  xa = xa * iv + selfA1[co] * vI[3 * n + 0] * mk;
  xb = xb * iv + selfA1[co] * vI[3 * n + 1] * mk;
  xc = xc * iv + selfA1[co] * vI[3 * n + 2] * mk;
  float nv = sqrtf(xa * xa + xb * xb + xc * xc + 1e-12f);
  float sc = fmaxf(nv + nbias1[co], 0.0f) / fmaxf(nv, EPSF);
  ws[OFF_H1N + idx * 3 + 0] = xa * sc;
  ws[OFF_H1N + idx * 3 + 1] = xb * sc;
  ws[OFF_H1N + idx * 3 + 2] = xc * sc;
}

// ---- fused B (2-edge PAIRED, 256 threads, grid 625 — best measured 119us) ----
__global__ __launch_bounds__(256) void k_passB(
    const float* __restrict__ wb01, const float* __restrict__ bb01,
    const float* __restrict__ wb11, const float* __restrict__ bb11,
    float* __restrict__ ws) {
  __shared__ __align__(16) float sW1a[64], sW1b[64], sc1[64], sc2[64];
  __shared__ __align__(16) float sW2T[2048];
  __shared__ __align__(16) float sPB01[1024];
  __shared__ __align__(16) float sPB11[3072];
  __shared__ float sBB01[32];
  __shared__ float sBB11[96];
  int tid = threadIdx.x;
  if (tid < 64) {
    sW1a[tid] = ws[OFF_FW1A + 128 + tid];
    sW1b[tid] = ws[OFF_FW1B + 128 + tid];
    sc1[tid] = ws[OFF_FC1 + 128 + tid];
    sc2[tid] = ws[OFF_FC2 + 128 + tid];
  }
  for (int t = tid; t < 2048; t += 256) sW2T[t] = ws[OFF_FW2T + 4096 + t];
  for (int t = tid; t < 1024; t += 256) {
    int i = t >> 5, c = t & 31;
    int o = c >> 4, ci = c & 15;
    sPB01[(ci * 2 + o) * 32 + i] = wb01[t];
  }
  for (int t = tid; t < 3072; t += 256) {
    int i = t / 96, c = t - i * 96;
    int o = c / 48, rem = c - o * 48;
    int ci = rem / 3, f = rem - ci * 3;
    sPB11[(ci * 6 + o * 3 + f) * 32 + i] = wb11[t];
  }
  if (tid < 32) {
    int o = tid >> 4, ci = tid & 15;
    sBB01[ci * 2 + o] = bb01[tid];
  }
  if (tid < 96) {
    int o = tid / 48, rem = tid - o * 48;
    int ci = rem / 3, f = rem - ci * 3;
    sBB11[ci * 6 + o * 3 + f] = bb11[tid];
  }
  __syncthreads();

  const int* srcs = (const int*)ws + OFF_SRCS;
  const float* wsrt = ws + OFF_WSRT;
  const float4* ecs = (const float4*)(ws + OFF_ECS);
  const int NP = NE / 2;
  int p = blockIdx.x * blockDim.x + tid;
  if (p >= NP) return;
  {
    int tA = 2 * p, tB = 2 * p + 1;
    int sA = srcs[tA], sB_ = srcs[tB];
    float4 EA = ecs[tA], EB = ecs[tB];
    float weA = wsrt[tA], weB = wsrt[tB];

    float HA[MID], HB[MID];
    mlpH2_lds(sW1a, sW1b, sc1, sc2, sW2T, weA, EA.x, weB, EB.x, HA, HB);
    const float* h0pA = ws + OFF_H0N + sA * CDIM;
    const float* h0pB = ws + OFF_H0N + sB_ * CDIM;
    float A0A = 0.0f, A1A = 0.0f, A0B = 0.0f, A1B = 0.0f;
#pragma unroll 1
    for (int ci = 0; ci < CDIM; ++ci) {
      float bA = h0pA[ci], bB = h0pB[ci];
      float R0A = sBB01[ci * 2 + 0], R1A = sBB01[ci * 2 + 1];
      float R0B = R0A, R1B = R1A;
      const float4* p0 = (const float4*)(sPB01 + (ci * 2 + 0) * 32);
      const float4* p1 = (const float4*)(sPB01 + (ci * 2 + 1) * 32);
#pragma unroll
      for (int i4 = 0; i4 < 8; ++i4) {
        float4 w0v = p0[i4], w1v = p1[i4];
        float hA0 = HA[4 * i4 + 0], hB0 = HB[4 * i4 + 0];
        float hA1 = HA[4 * i4 + 1], hB1 = HB[4 * i4 + 1];
        float hA2 = HA[4 * i4 + 2], hB2 = HB[4 * i4 + 2];
        float hA3 = HA[4 * i4 + 3], hB3 = HB[4 * i4 + 3];
        R0A = fmaf(hA0, w0v.x, R0A); R0B = fmaf(hB0, w0v.x, R0B);
        R1A = fmaf(hA0, w1v.x, R1A); R1B = fmaf(hB0, w1v.x, R1B);
        R0A = fmaf(hA1, w0v.y, R0A); R0B = fmaf(hB1, w0v.y, R0B);
        R1A = fmaf(hA1, w1v.y, R1A); R1B = fmaf(hB1, w1v.y, R1B);
        R0A = fmaf(hA2, w0v.z, R0A); R0B = fmaf(hB2, w0v.z, R0B);
        R1A = fmaf(hA2, w1v.z, R1A); R1B = fmaf(hB2, w1v.z, R1B);
        R0A = fmaf(hA3, w0v.w, R0A); R0B = fmaf(hB3, w0v.w, R0B);
        R1A = fmaf(hA3, w1v.w, R1A); R1B = fmaf(hB3, w1v.w, R1B);
      }
      A0A = fmaf(R0A, bA, A0A); A1A = fmaf(R1A, bA, A1A);
      A0B = fmaf(R0B, bB, A0B); A1B = fmaf(R1B, bB, A1B);
      SCHED_FENCE();
    }
    mlpH2_lds(sW1a + 32, sW1b + 32, sc1 + 32, sc2 + 32, sW2T + 1024,
              weA, EA.x, weB, EB.x, HA, HB);
    const float* h1pA = ws + OFF_H1N + sA * CDIM * 3;
    const float* h1pB = ws + OFF_H1N + sB_ * CDIM * 3;
    float GA[6][3], GB[6][3];
#pragma unroll
    for (int of = 0; of < 6; ++of) {
      GA[of][0] = 0.0f; GA[of][1] = 0.0f; GA[of][2] = 0.0f;
      GB[of][0] = 0.0f; GB[of][1] = 0.0f; GB[of][2] = 0.0f;
    }
#pragma unroll 1
    for (int ci = 0; ci < CDIM; ++ci) {
      float bA0 = h1pA[ci * 3 + 0], bA1 = h1pA[ci * 3 + 1], bA2 = h1pA[ci * 3 + 2];
      float bB0 = h1pB[ci * 3 + 0], bB1 = h1pB[ci * 3 + 1], bB2 = h1pB[ci * 3 + 2];
#pragma unroll
      for (int of = 0; of < 6; ++of) {
        float RA = sBB11[ci * 6 + of];
        float RB = RA;
        const float4* wp = (const float4*)(sPB11 + (ci * 6 + of) * 32);
#pragma unroll
        for (int i4 = 0; i4 < 8; ++i4) {
          float4 wv = wp[i4];
          RA = fmaf(HA[4 * i4 + 0], wv.x, RA);
          RB = fmaf(HB[4 * i4 + 0], wv.x, RB);
          RA = fmaf(HA[4 * i4 + 1], wv.y, RA);
          RB = fmaf(HB[4 * i4 + 1], wv.y, RB);
          RA = fmaf(HA[4 * i4 + 2], wv.z, RA);
          RB = fmaf(HB[4 * i4 + 2], wv.z, RB);
          RA = fmaf(HA[4 * i4 + 3], wv.w, RA);
          RB = fmaf(HB[4 * i4 + 3], wv.w, RB);
        }
        GA[of][0] = fmaf(RA, bA0, GA[of][0]);
        GA[of][1] = fmaf(RA, bA1, GA[of][1]);
        GA[of][2] = fmaf(RA, bA2, GA[of][2]);
        GB[of][0] = fmaf(RB, bB0, GB[of][0]);
        GB[of][1] = fmaf(RB, bB1, GB[of][1]);
        GB[of][2] = fmaf(RB, bB2, GB[of][2]);
      }
      SCHED_FENCE();
    }
    {
      float ux = EA.y, uy = EA.z, uz = EA.w;
      float y10 = Y1C * uy, y11 = Y1C * uz, y12 = Y1C * ux;
      float y20 = Y2C1 * ux * uy, y21 = Y2C1 * uy * uz;
      float y22 = Y2C2 * (3.0f * uz * uz - 1.0f);
      float y23 = Y2C1 * ux * uz, y24 = Y2C3 * (ux * ux - uy * uy);
      float S00 = -S6C * y22 - S2C * y24;
      float S11 = 2.0f * S6C * y22;
      float S22 = -S6C * y22 + S2C * y24;
      float S01 = S2C * y21, S02 = S2C * y20, S12 = S2C * y23;
      float4* mp = (float4*)(ws + OFF_MSGB) + tA * 2;
#pragma unroll
      for (int o = 0; o < 2; ++o) {
        float Ao = (o == 0) ? A0A : A1A;
        float m0 = Ao * y10 + K0C * GA[o * 3 + 0][0]
                 + S2C * (y12 * GA[o * 3 + 1][1] - y11 * GA[o * 3 + 1][2])
                 + S00 * GA[o * 3 + 2][0] + S01 * GA[o * 3 + 2][1] + S02 * GA[o * 3 + 2][2];
        float m1 = Ao * y11 + K0C * GA[o * 3 + 0][1]
                 + S2C * (y10 * GA[o * 3 + 1][2] - y12 * GA[o * 3 + 1][0])
                 + S01 * GA[o * 3 + 2][0] + S11 * GA[o * 3 + 2][1] + S12 * GA[o * 3 + 2][2];
        float m2 = Ao * y12 + K0C * GA[o * 3 + 0][2]
                 + S2C * (y11 * GA[o * 3 + 1][0] - y10 * GA[o * 3 + 1][1])
                 + S02 * GA[o * 3 + 2][0] + S12 * GA[o * 3 + 2][1] + S22 * GA[o * 3 + 2][2];
        mp[o] = make_float4(m0, m1, m2, 0.0f);
      }
    }
    {
      float ux = EB.y, uy = EB.z, uz = EB.w;
      float y10 = Y1C * uy, y11 = Y1C * uz, y12 = Y1C * ux;
      float y20 = Y2C1 * ux * uy, y21 = Y2C1 * uy * uz;
      float y22 = Y2C2 * (3.0f * uz * uz - 1.0f);
      float y23 = Y2C1 * ux * uz, y24 = Y2C3 * (ux * ux - uy * uy);
      float S00 = -S6C * y22 - S2C * y24;
      float S11 = 2.0f * S6C * y22;
      float S22 = -S6C * y22 + S2C * y24;
      float S01 = S2C * y21, S02 = S2C * y20, S12 = S2C * y23;
      float4* mp = (float4*)(ws + OFF_MSGB) + tB * 2;
#pragma unroll
      for (int o = 0; o < 2; ++o) {
        float Ao = (o == 0) ? A0B : A1B;
        float m0 = Ao * y10 + K0C * GB[o * 3 + 0][0]
                 + S2C * (y12 * GB[o * 3 + 1][1] - y11 * GB[o * 3 + 1][2])
                 + S00 * GB[o * 3 + 2][0] + S01 * GB[o * 3 + 2][1] + S02 * GB[o * 3 + 2][2];
        float m1 = Ao * y11 + K0C * GB[o * 3 + 0][1]
                 + S2C * (y10 * GB[o * 3 + 1][2] - y12 * GB[o * 3 + 1][0])
                 + S01 * GB[o * 3 + 2][0] + S11 * GB[o * 3 + 2][1] + S12 * GB[o * 3 + 2][2];
        float m2 = Ao * y12 + K0C * GB[o * 3 + 0][2]
                 + S2C * (y11 * GB[o * 3 + 1][0] - y10 * GB[o * 3 + 1][1])
                 + S02 * GB[o * 3 + 2][0] + S12 * GB[o * 3 + 2][1] + S22 * GB[o * 3 + 2][2];
        mp[o] = make_float4(m0, m1, m2, 0.0f);
      }
    }
  }
}

// ---- nodeB ----
__global__ __launch_bounds__(256) void k_nodeB(
    const float* __restrict__ selfB1, float* __restrict__ out,
    const float* __restrict__ ws) {
  int idx = blockIdx.x * blockDim.x + threadIdx.x;
  if (idx >= NN * 6) return;
  int n = idx / 6;
  int q = idx - n * 6;
  int o = q / 3, a = q - o * 3;
  const int* rowptr = (const int*)ws + OFF_ROWPTR;
  int r0 = rowptr[n], r1 = rowptr[n + 1];
  const float* msgB = ws + OFF_MSGB;
  int col = o * 4 + a;
  float sum = 0.0f;
  for (int row = r0; row < r1; ++row) sum += msgB[row * 8 + col];
  float dg = (float)(r1 - r0);
  float iv = 1.0f / fmaxf(dg, 1.0f);
  float mk = dg > 0.0f ? 1.0f : 0.0f;
  const float* h1p = ws + OFF_H1N + n * CDIM * 3;
  float self = 0.0f;
#pragma unroll
  for (int ci = 0; ci < CDIM; ++ci)
    self = fmaf(selfB1[o * CDIM + ci], h1p[ci * 3 + a], self);
  out[idx] = sum * iv + self * mk;
}

extern "C" void kernel_launch(void* const* d_in, const int* in_sizes, int n_in,
                              void* d_out, int out_size, void* d_ws, size_t ws_size,
                              hipStream_t stream) {
  (void)in_sizes; (void)n_in; (void)out_size; (void)ws_size;
  const int* src = (const int*)d_in[0];
  const int* dst = (const int*)d_in[1];
  const float* pos = (const float*)d_in[2];
  const float* cI = (const float*)d_in[3];
  const float* vI = (const float*)d_in[4];
  const float* w = (const float*)d_in[5];
  const float* rW1 = (const float*)d_in[6];
  const float* rb1 = (const float*)d_in[7];
  const float* rg1 = (const float*)d_in[8];
  const float* rbe1 = (const float*)d_in[9];
  const float* rW2 = (const float*)d_in[10];
  const float* rb2 = (const float*)d_in[11];
  const float* rg2 = (const float*)d_in[12];
  const float* rbe2 = (const float*)d_in[13];
  const float* w3_a00 = (const float*)d_in[14];
  const float* b3_a00 = (const float*)d_in[15];
  const float* w3_a01 = (const float*)d_in[16];
  const float* b3_a01 = (const float*)d_in[17];
  const float* w3_a10 = (const float*)d_in[18];
  const float* b3_a10 = (const float*)d_in[19];
  const float* w3_a11 = (const float*)d_in[20];
  const float* b3_a11 = (const float*)d_in[21];
  const float* w3_b01 = (const float*)d_in[22];
  const float* b3_b01 = (const float*)d_in[23];
  const float* w3_b11 = (const float*)d_in[24];
  const float* b3_b11 = (const float*)d_in[25];
  const float* selfA0 = (const float*)d_in[26];
  const float* selfA1 = (const float*)d_in[27];
  const float* selfB1 = (const float*)d_in[28];
  const float* nbias0 = (const float*)d_in[29];
  const float* nbias1 = (const float*)d_in[30];
  float* ws = (float*)d_ws;
  float* out = (float*)d_out;

  hipMemsetAsync(d_ws, 0, (size_t)ZERO_WORDS * 4, stream);

  k_hist<<<1250, 256, 0, stream>>>(dst, ws);
  k_scan1<<<NBLK, 256, 0, stream>>>(ws);
  k_scan2<<<1, 128, 0, stream>>>(ws);
  k_scan3<<<NBLK, 256, 0, stream>>>(ws);
  k_scatter<<<1250, 256, 0, stream>>>(dst, ws);
  k_geo<<<1250, 256, 0, stream>>>(src, dst, pos, w, ws);
  k_fin1<<<1, 192, 0, stream>>>(rW1, rb1, rg1, rbe1, ws);
  k_stats2<<<dim3(256, 6, 2), 256, 0, stream>>>(rW2, rb2, ws);
  k_fin2<<<1, 192, 0, stream>>>(rb2, rg2, rbe2, ws);
  k_fold2<<<24, 256, 0, stream>>>(rW2, ws);
  k_passA0<<<1250, 256, 0, stream>>>(cI, vI, w3_a00, b3_a00, w3_a10, b3_a10, ws);
  k_passA1<<<1250, 256, 0, stream>>>(cI, vI, w3_a01, b3_a01, w3_a11, b3_a11, ws);
  k_nodeA<<<1250, 256, 0, stream>>>(cI, vI, selfA0, selfA1, nbias0, nbias1, ws);
  k_passB<<<625, 256, 0, stream>>>(w3_b01, b3_b01, w3_b11, b3_b11, ws);
  k_nodeB<<<469, 256, 0, stream>>>(selfB1, out, ws);
}